// Round 1
// baseline (1159.196 us; speedup 1.0000x reference)
//
#include <hip/hip_runtime.h>
#include <math.h>

// Problem constants
#define B_ 8
#define S_ 1024
#define D_ 768
#define H_ 12
#define HD_ 64
#define M_ 8192   // B_*S_

// ---------------------------------------------------------------------------
// RoPE table: tab[s][k2][2] ; k2<16 -> row-angle pair k2, k2>=16 -> col-angle
// ---------------------------------------------------------------------------
__global__ void rope_tab_kernel(float* __restrict__ tab) {
  int idx = blockIdx.x * 256 + threadIdx.x;     // 0..32767
  if (idx >= 32768) return;
  int s  = idx >> 5, k2 = idx & 31;
  int r  = s >> 5,  c  = s & 31;
  int j  = k2 & 15;
  float f   = expf(-(float)j * (9.210340371976184f / 16.0f)); // 10000^(-j/16)
  float pos = (k2 < 16) ? (float)r : (float)c;
  float a   = pos * f;
  tab[2*idx]   = cosf(a);
  tab[2*idx+1] = sinf(a);
}

// ---------------------------------------------------------------------------
// Fused QKV projection GEMM. M=8192, N=2304 (Wq|Wk|Wv), K=768.
// 128x128 tile, 256 threads, 8x8 per thread, K-step 16.
// Epilogue: bias + 2D RoPE (q,k) + fold 1/8 into q; write [B,H,S,64] layout.
// ---------------------------------------------------------------------------
__global__ __launch_bounds__(256) void qkv_kernel(
    const float* __restrict__ x,
    const float* __restrict__ Wq, const float* __restrict__ bq,
    const float* __restrict__ Wk, const float* __restrict__ bk,
    const float* __restrict__ Wv, const float* __restrict__ bv,
    const float* __restrict__ tab,
    float* __restrict__ qws, float* __restrict__ kws, float* __restrict__ vws) {
  __shared__ float As[16][132];   // [k][m], padded
  __shared__ float Bs[16][132];   // [k][n], padded
  const int t  = threadIdx.x;
  const int m0 = blockIdx.x * 128;
  const int n0 = blockIdx.y * 128;
  const int proj = n0 / 768;
  const int col0 = n0 % 768;
  const float* W    = (proj == 0) ? Wq : (proj == 1) ? Wk : Wv;
  const float* bias = (proj == 0) ? bq : (proj == 1) ? bk : bv;
  const int ty = t >> 4, tx = t & 15;

  float acc[8][8];
#pragma unroll
  for (int i = 0; i < 8; ++i)
#pragma unroll
    for (int j = 0; j < 8; ++j) acc[i][j] = 0.f;

  for (int k0 = 0; k0 < 768; k0 += 16) {
    __syncthreads();
#pragma unroll
    for (int r2 = 0; r2 < 2; ++r2) {
      int q  = t + r2 * 256;
      int mi = q >> 2, kq = q & 3;
      float4 f = *(const float4*)(x + (size_t)(m0 + mi) * 768 + k0 + kq * 4);
      As[kq*4+0][mi] = f.x; As[kq*4+1][mi] = f.y;
      As[kq*4+2][mi] = f.z; As[kq*4+3][mi] = f.w;
      int kk = q >> 5, nq = q & 31;
      *(float4*)&Bs[kk][nq*4] =
          *(const float4*)(W + (size_t)(k0 + kk) * 768 + col0 + nq * 4);
    }
    __syncthreads();
#pragma unroll
    for (int kk = 0; kk < 16; ++kk) {
      float a[8], b[8];
      *(float4*)&a[0] = *(const float4*)&As[kk][ty*8];
      *(float4*)&a[4] = *(const float4*)&As[kk][ty*8+4];
      *(float4*)&b[0] = *(const float4*)&Bs[kk][tx*8];
      *(float4*)&b[4] = *(const float4*)&Bs[kk][tx*8+4];
#pragma unroll
      for (int i = 0; i < 8; ++i)
#pragma unroll
        for (int j = 0; j < 8; ++j) acc[i][j] += a[i] * b[j];
    }
  }

  // Epilogue
  const int colb = col0 + tx * 8;      // multiple of 8, within one head
  const int h  = colb >> 6;
  const int d0 = colb & 63;
  float bv8[8];
#pragma unroll
  for (int j = 0; j < 8; ++j) bv8[j] = bias[colb + j];
  float* outp = (proj == 0) ? qws : (proj == 1) ? kws : vws;

#pragma unroll
  for (int i = 0; i < 8; ++i) {
    int m = m0 + ty * 8 + i;
    int b = m >> 10, s = m & 1023;
    float v8[8];
#pragma unroll
    for (int j = 0; j < 8; ++j) v8[j] = acc[i][j] + bv8[j];
    if (proj < 2) {
#pragma unroll
      for (int jp = 0; jp < 8; jp += 2) {
        int d    = d0 + jp;
        int kidx = (d < 32) ? (d >> 1) : (16 + ((d - 32) >> 1));
        float cs = tab[2*(s*32 + kidx)];
        float sn = tab[2*(s*32 + kidx) + 1];
        float e = v8[jp], o = v8[jp+1];
        v8[jp]   = e * cs - o * sn;
        v8[jp+1] = e * sn + o * cs;
      }
      if (proj == 0) {
#pragma unroll
        for (int j = 0; j < 8; ++j) v8[j] *= 0.125f;  // fold 1/sqrt(64)
      }
    }
    size_t off = ((size_t)(b * 12 + h) * 1024 + s) * 64 + d0;
    *(float4*)&outp[off]     = make_float4(v8[0], v8[1], v8[2], v8[3]);
    *(float4*)&outp[off + 4] = make_float4(v8[4], v8[5], v8[6], v8[7]);
  }
}

// ---------------------------------------------------------------------------
// Flash attention: one block = one (b,h) x 64 q-rows; iterate 16 K/V tiles.
// 256 thr: tx(0..15) key/dim cols, ty(0..15) q rows; 4x4 register tiles.
// ks[] buffer is reused to hold P after the score phase (LDS <= 64KB).
// ---------------------------------------------------------------------------
__global__ __launch_bounds__(256) void attn_kernel(
    const float* __restrict__ qws, const float* __restrict__ kws,
    const float* __restrict__ vws, float* __restrict__ ows) {
  __shared__ float qs[64][68];
  __shared__ float ks[64][68];   // K tile, then P tile
  __shared__ float vs[64][68];
  const int t  = threadIdx.x;
  const int qc = blockIdx.x & 15;
  const int bh = blockIdx.x >> 4;
  const int tx = t & 15, ty = t >> 4;

  const float* qbase = qws + ((size_t)bh * 1024 + qc * 64) * 64;
#pragma unroll
  for (int r = 0; r < 4; ++r) {
    int e = t + 256 * r;
    int row = e >> 4, dq = e & 15;
    *(float4*)&qs[row][dq*4] = *(const float4*)&qbase[row * 64 + dq * 4];
  }

  float m_run[4], l_run[4], o[4][4];
#pragma unroll
  for (int i = 0; i < 4; ++i) {
    m_run[i] = -1e30f; l_run[i] = 0.f;
#pragma unroll
    for (int j = 0; j < 4; ++j) o[i][j] = 0.f;
  }

  for (int kt = 0; kt < 16; ++kt) {
    __syncthreads();   // prev iter done reading ks/vs (and q visible, kt=0)
    const float* kb = kws + ((size_t)bh * 1024 + kt * 64) * 64;
    const float* vb = vws + ((size_t)bh * 1024 + kt * 64) * 64;
#pragma unroll
    for (int r = 0; r < 4; ++r) {
      int e = t + 256 * r;
      int row = e >> 4, dq = e & 15;
      *(float4*)&ks[row][dq*4] = *(const float4*)&kb[row * 64 + dq * 4];
      *(float4*)&vs[row][dq*4] = *(const float4*)&vb[row * 64 + dq * 4];
    }
    __syncthreads();

    // ---- scores: S[i][j] = q_row(ty*4+i) . k_row(tx*4+j) (q pre-scaled) ----
    float sacc[4][4];
#pragma unroll
    for (int i = 0; i < 4; ++i)
#pragma unroll
      for (int j = 0; j < 4; ++j) sacc[i][j] = 0.f;
#pragma unroll
    for (int d0 = 0; d0 < 64; d0 += 4) {
      float4 qv[4], kv[4];
#pragma unroll
      for (int i = 0; i < 4; ++i) qv[i] = *(float4*)&qs[ty*4+i][d0];
#pragma unroll
      for (int j = 0; j < 4; ++j) kv[j] = *(float4*)&ks[tx*4+j][d0];
#pragma unroll
      for (int i = 0; i < 4; ++i)
#pragma unroll
        for (int j = 0; j < 4; ++j)
          sacc[i][j] += qv[i].x*kv[j].x + qv[i].y*kv[j].y +
                        qv[i].z*kv[j].z + qv[i].w*kv[j].w;
    }
    __syncthreads();   // all done reading ks -> safe to overwrite with P

    // ---- online softmax (row reduce across the 16 tx lanes) ----
#pragma unroll
    for (int i = 0; i < 4; ++i) {
      float mt = fmaxf(fmaxf(sacc[i][0], sacc[i][1]),
                       fmaxf(sacc[i][2], sacc[i][3]));
#pragma unroll
      for (int off = 1; off < 16; off <<= 1)
        mt = fmaxf(mt, __shfl_xor(mt, off));
      float mn   = fmaxf(m_run[i], mt);
      float corr = __expf(m_run[i] - mn);
      m_run[i] = mn;
      float p0 = __expf(sacc[i][0] - mn);
      float p1 = __expf(sacc[i][1] - mn);
      float p2 = __expf(sacc[i][2] - mn);
      float p3 = __expf(sacc[i][3] - mn);
      float ls = p0 + p1 + p2 + p3;
#pragma unroll
      for (int off = 1; off < 16; off <<= 1)
        ls += __shfl_xor(ls, off);
      l_run[i] = l_run[i] * corr + ls;
#pragma unroll
      for (int j = 0; j < 4; ++j) o[i][j] *= corr;
      *(float4*)&ks[ty*4+i][tx*4] = make_float4(p0, p1, p2, p3);
    }
    __syncthreads();

    // ---- PV: o[i][t] += P[i][j] * V[j][t] ----
#pragma unroll
    for (int j0 = 0; j0 < 64; j0 += 4) {
      float4 pv4[4], vv4[4];
#pragma unroll
      for (int i = 0; i < 4; ++i)  pv4[i] = *(float4*)&ks[ty*4+i][j0];
#pragma unroll
      for (int jj = 0; jj < 4; ++jj) vv4[jj] = *(float4*)&vs[j0+jj][tx*4];
#pragma unroll
      for (int i = 0; i < 4; ++i) {
        float pj[4] = {pv4[i].x, pv4[i].y, pv4[i].z, pv4[i].w};
#pragma unroll
        for (int jj = 0; jj < 4; ++jj) {
          o[i][0] += pj[jj] * vv4[jj].x;
          o[i][1] += pj[jj] * vv4[jj].y;
          o[i][2] += pj[jj] * vv4[jj].z;
          o[i][3] += pj[jj] * vv4[jj].w;
        }
      }
    }
  }

  // epilogue: normalize, write [B,S,H*64] layout for the output projection
  const int b = bh / 12, h = bh % 12;
#pragma unroll
  for (int i = 0; i < 4; ++i) {
    int s = qc * 64 + ty * 4 + i;
    float inv = 1.f / l_run[i];
    *(float4*)&ows[((size_t)(b * 1024 + s)) * 768 + h * 64 + tx * 4] =
        make_float4(o[i][0]*inv, o[i][1]*inv, o[i][2]*inv, o[i][3]*inv);
  }
}

// ---------------------------------------------------------------------------
// Output projection GEMM: C = A(8192x768) @ Wo(768x768) + bo
// ---------------------------------------------------------------------------
__global__ __launch_bounds__(256) void proj_kernel(
    const float* __restrict__ A, const float* __restrict__ W,
    const float* __restrict__ bias, float* __restrict__ C) {
  __shared__ float As[16][132];
  __shared__ float Bs[16][132];
  const int t  = threadIdx.x;
  const int m0 = blockIdx.x * 128;
  const int n0 = blockIdx.y * 128;
  const int ty = t >> 4, tx = t & 15;

  float acc[8][8];
#pragma unroll
  for (int i = 0; i < 8; ++i)
#pragma unroll
    for (int j = 0; j < 8; ++j) acc[i][j] = 0.f;

  for (int k0 = 0; k0 < 768; k0 += 16) {
    __syncthreads();
#pragma unroll
    for (int r2 = 0; r2 < 2; ++r2) {
      int q  = t + r2 * 256;
      int mi = q >> 2, kq = q & 3;
      float4 f = *(const float4*)(A + (size_t)(m0 + mi) * 768 + k0 + kq * 4);
      As[kq*4+0][mi] = f.x; As[kq*4+1][mi] = f.y;
      As[kq*4+2][mi] = f.z; As[kq*4+3][mi] = f.w;
      int kk = q >> 5, nq = q & 31;
      *(float4*)&Bs[kk][nq*4] =
          *(const float4*)(W + (size_t)(k0 + kk) * 768 + n0 + nq * 4);
    }
    __syncthreads();
#pragma unroll
    for (int kk = 0; kk < 16; ++kk) {
      float a[8], b[8];
      *(float4*)&a[0] = *(const float4*)&As[kk][ty*8];
      *(float4*)&a[4] = *(const float4*)&As[kk][ty*8+4];
      *(float4*)&b[0] = *(const float4*)&Bs[kk][tx*8];
      *(float4*)&b[4] = *(const float4*)&Bs[kk][tx*8+4];
#pragma unroll
      for (int i = 0; i < 8; ++i)
#pragma unroll
        for (int j = 0; j < 8; ++j) acc[i][j] += a[i] * b[j];
    }
  }

  float bv8[8];
#pragma unroll
  for (int j = 0; j < 8; ++j) bv8[j] = bias[n0 + tx*8 + j];
#pragma unroll
  for (int i = 0; i < 8; ++i) {
    int m = m0 + ty * 8 + i;
    float v8[8];
#pragma unroll
    for (int j = 0; j < 8; ++j) v8[j] = acc[i][j] + bv8[j];
    *(float4*)&C[(size_t)m * 768 + n0 + tx*8]     =
        make_float4(v8[0], v8[1], v8[2], v8[3]);
    *(float4*)&C[(size_t)m * 768 + n0 + tx*8 + 4] =
        make_float4(v8[4], v8[5], v8[6], v8[7]);
  }
}

// ---------------------------------------------------------------------------
extern "C" void kernel_launch(void* const* d_in, const int* in_sizes, int n_in,
                              void* d_out, int out_size, void* d_ws, size_t ws_size,
                              hipStream_t stream) {
  const float* x  = (const float*)d_in[0];
  const float* Wq = (const float*)d_in[1];
  const float* bq = (const float*)d_in[2];
  const float* Wk = (const float*)d_in[3];
  const float* bk = (const float*)d_in[4];
  const float* Wv = (const float*)d_in[5];
  const float* bv = (const float*)d_in[6];
  const float* Wo = (const float*)d_in[7];
  const float* bo = (const float*)d_in[8];
  float* out = (float*)d_out;

  float* ws  = (float*)d_ws;
  float* tab = ws;                       // 65536 floats (256 KB)
  float* qws = ws + 65536;               // 6291456 floats each
  float* kws = qws + 6291456;
  float* vws = kws + 6291456;
  float* aws = vws + 6291456;            // attention output [B,S,768]

  rope_tab_kernel<<<dim3(128), dim3(256), 0, stream>>>(tab);
  qkv_kernel<<<dim3(64, 18), dim3(256), 0, stream>>>(
      x, Wq, bq, Wk, bk, Wv, bv, tab, qws, kws, vws);
  attn_kernel<<<dim3(1536), dim3(256), 0, stream>>>(qws, kws, vws, aws);
  proj_kernel<<<dim3(64, 6), dim3(256), 0, stream>>>(aws, Wo, bo, out);
}

// Round 2
// 799.158 us; speedup vs baseline: 1.4505x; 1.4505x over previous
//
#include <hip/hip_runtime.h>
#include <hip/hip_bf16.h>
#include <math.h>

// Problem constants
#define B_ 8
#define S_ 1024
#define D_ 768
#define H_ 12
#define HD_ 64
#define M_ 8192   // B_*S_

typedef __attribute__((ext_vector_type(8))) short short8;
typedef __attribute__((ext_vector_type(4))) float floatx4;

typedef const unsigned int __attribute__((address_space(1))) as1_cu32;
typedef unsigned int __attribute__((address_space(3))) as3_u32;

// ---------------- bf16 split helpers ----------------
__device__ __forceinline__ unsigned short bfh(float x) {
  __hip_bfloat16 b = __float2bfloat16(x);
  union { __hip_bfloat16 b; unsigned short u; } c; c.b = b; return c.u;
}
__device__ __forceinline__ float bf2f(unsigned short u) {
  union { unsigned u; float f; } a; a.u = ((unsigned)u) << 16; return a.f;
}
__device__ __forceinline__ void bsplit(float x, unsigned short& h, unsigned short& l) {
  h = bfh(x);
  l = bfh(x - bf2f(h));
}

// ---------------------------------------------------------------------------
// RoPE table: tab[s][k2][2] ; k2<16 -> row-angle pair k2, k2>=16 -> col-angle
// ---------------------------------------------------------------------------
__global__ void rope_tab_kernel(float* __restrict__ tab) {
  int idx = blockIdx.x * 256 + threadIdx.x;     // 0..32767
  if (idx >= 32768) return;
  int s  = idx >> 5, k2 = idx & 31;
  int r  = s >> 5,  c  = s & 31;
  int j  = k2 & 15;
  float f   = expf(-(float)j * (9.210340371976184f / 16.0f)); // 10000^(-j/16)
  float pos = (k2 < 16) ? (float)r : (float)c;
  float a   = pos * f;
  tab[2*idx]   = cosf(a);
  tab[2*idx+1] = sinf(a);
}

// ---------------------------------------------------------------------------
// Convert x (f32) -> hi/lo bf16, row-major [M][768]
// ---------------------------------------------------------------------------
__global__ __launch_bounds__(256) void xconv_kernel(
    const float* __restrict__ x, unsigned short* __restrict__ xh,
    unsigned short* __restrict__ xl) {
  int i = (blockIdx.x * 256 + threadIdx.x) * 4;
  float4 f = *(const float4*)&x[i];
  ushort4 h, l;
  bsplit(f.x, h.x, l.x); bsplit(f.y, h.y, l.y);
  bsplit(f.z, h.z, l.z); bsplit(f.w, h.w, l.w);
  *(ushort4*)&xh[i] = h;
  *(ushort4*)&xl[i] = l;
}

// ---------------------------------------------------------------------------
// Convert+transpose W [K=768][N=768] f32 -> Wt hi/lo [N][K] bf16.
// z = 0,1,2 -> Wq,Wk,Wv packed into wth/wtl rows z*768.. ; z=3 -> Wo.
// ---------------------------------------------------------------------------
__global__ __launch_bounds__(256) void wconv_kernel(
    const float* __restrict__ Wq, const float* __restrict__ Wk,
    const float* __restrict__ Wv, const float* __restrict__ Wo,
    unsigned short* __restrict__ wth, unsigned short* __restrict__ wtl,
    unsigned short* __restrict__ woh, unsigned short* __restrict__ wol) {
  __shared__ float tile[32][33];
  int z = blockIdx.z;
  const float* src = (z == 0) ? Wq : (z == 1) ? Wk : (z == 2) ? Wv : Wo;
  unsigned short* dh = (z < 3) ? wth + (size_t)z * 768 * 768 : woh;
  unsigned short* dl = (z < 3) ? wtl + (size_t)z * 768 * 768 : wol;
  int k0 = blockIdx.x * 32, n0 = blockIdx.y * 32;
  int tx = threadIdx.x & 31, ty = threadIdx.x >> 5;   // ty 0..7
#pragma unroll
  for (int r = 0; r < 4; ++r)
    tile[ty + r * 8][tx] = src[(size_t)(k0 + ty + r * 8) * 768 + n0 + tx];
  __syncthreads();
#pragma unroll
  for (int r = 0; r < 4; ++r) {
    int n = n0 + ty + r * 8;
    float v = tile[tx][ty + r * 8];
    unsigned short h, l; bsplit(v, h, l);
    dh[(size_t)n * 768 + k0 + tx] = h;
    dl[(size_t)n * 768 + k0 + tx] = l;
  }
}

// ---------------------------------------------------------------------------
// MFMA GEMM core pieces (128x128 tile, BK=32, 4 waves, bf16x3).
// LDS tile layout: 16B chunk c -> row m=c>>2, slot s=c&3; slot holds global
// k-chunk g = s ^ (m&3)  (XOR swizzle -> conflict-free ds_read_b128).
// Both A and B sources are [rows][768] bf16 row-major (K contiguous).
// ---------------------------------------------------------------------------
__device__ __forceinline__ void stage_tile(const unsigned short* __restrict__ src,
                                           int row0, int k0, short* lds, int t) {
  int l  = t & 63;
  int wb = t & 192;                 // wave-uniform
#pragma unroll
  for (int r = 0; r < 2; ++r) {
    int cbase = r * 256 + wb;       // wave's first chunk
    int c = cbase + l;
    int m = c >> 2, s = c & 3;
    int g = s ^ (m & 3);
    const unsigned short* gp = src + (size_t)(row0 + m) * 768 + k0 + g * 8;
    __builtin_amdgcn_global_load_lds((as1_cu32*)(const void*)gp,
                                     (as3_u32*)(void*)(lds + cbase * 8),
                                     16, 0, 0);
  }
}

// Main loop: fills acc[4][4] (each 16x16 frag, D row=(l>>4)*4+r, col=l&15).
#define GEMM_MAIN_LOOP(Ah, Al, Bh, Bl, m0, n0)                                   \
  floatx4 acc[4][4];                                                             \
  _Pragma("unroll") for (int i = 0; i < 4; ++i)                                  \
      _Pragma("unroll") for (int j = 0; j < 4; ++j)                              \
          acc[i][j] = (floatx4){0.f, 0.f, 0.f, 0.f};                             \
  const int l  = t & 63;                                                         \
  const int lm = l & 15, g = l >> 4;                                             \
  const int wm = ((t >> 7) & 1) * 64, wn = ((t >> 6) & 1) * 64;                  \
  const int sl = g ^ (lm & 3);                                                   \
  for (int k0 = 0; k0 < 768; k0 += 32) {                                         \
    __syncthreads();                                                             \
    stage_tile(Ah, m0, k0, sAh, t);                                              \
    stage_tile(Al, m0, k0, sAl, t);                                              \
    stage_tile(Bh, n0, k0, sBh, t);                                              \
    stage_tile(Bl, n0, k0, sBl, t);                                              \
    __syncthreads();                                                             \
    short8 ah[4], al[4];                                                         \
    _Pragma("unroll") for (int i = 0; i < 4; ++i) {                              \
      int ra = wm + i * 16 + lm;                                                 \
      ah[i] = *(const short8*)&sAh[ra * 32 + sl * 8];                            \
      al[i] = *(const short8*)&sAl[ra * 32 + sl * 8];                            \
    }                                                                            \
    _Pragma("unroll") for (int j = 0; j < 4; ++j) {                              \
      int rb = wn + j * 16 + lm;                                                 \
      short8 bh = *(const short8*)&sBh[rb * 32 + sl * 8];                        \
      short8 bl = *(const short8*)&sBl[rb * 32 + sl * 8];                        \
      _Pragma("unroll") for (int i = 0; i < 4; ++i) {                            \
        acc[i][j] = __builtin_amdgcn_mfma_f32_16x16x32_bf16(ah[i], bh, acc[i][j], 0, 0, 0); \
        acc[i][j] = __builtin_amdgcn_mfma_f32_16x16x32_bf16(ah[i], bl, acc[i][j], 0, 0, 0); \
        acc[i][j] = __builtin_amdgcn_mfma_f32_16x16x32_bf16(al[i], bh, acc[i][j], 0, 0, 0); \
      }                                                                          \
    }                                                                            \
  }

// ---------------------------------------------------------------------------
// QKV projection (MFMA): M=8192, N=2304 (q|k|v), K=768.
// Epilogue: bias + 2D RoPE (q,k) + 1/8 into q; write fp32 [B,H,S,64].
// ---------------------------------------------------------------------------
__global__ __launch_bounds__(256) void qkv_mfma_kernel(
    const unsigned short* __restrict__ xh, const unsigned short* __restrict__ xl,
    const unsigned short* __restrict__ wth, const unsigned short* __restrict__ wtl,
    const float* __restrict__ bq, const float* __restrict__ bk,
    const float* __restrict__ bv, const float* __restrict__ tab,
    float* __restrict__ qws, float* __restrict__ kws, float* __restrict__ vws) {
  __shared__ __align__(16) short sAh[4096], sAl[4096], sBh[4096], sBl[4096];
  const int t  = threadIdx.x;
  const int m0 = blockIdx.x * 128;
  const int n0 = blockIdx.y * 128;

  GEMM_MAIN_LOOP(xh, xl, wth, wtl, m0, n0)

  const int proj = n0 / 768;
  const int col0 = n0 % 768;
  const float* bias = (proj == 0) ? bq : (proj == 1) ? bk : bv;
  float* outp = (proj == 0) ? qws : (proj == 1) ? kws : vws;
  const float qs = (proj == 0) ? 0.125f : 1.f;

#pragma unroll
  for (int j = 0; j < 4; ++j) {
    int colf = col0 + wn + j * 16;
    int hh = colf >> 6;
    int d  = (colf & 63) + lm;
    float bsv = bias[colf + lm];
    int kidx = (d < 32) ? (d >> 1) : (16 + ((d - 32) >> 1));
    float sgn = (d & 1) ? 1.f : -1.f;
#pragma unroll
    for (int i = 0; i < 4; ++i) {
#pragma unroll
      for (int r = 0; r < 4; ++r) {
        int m = m0 + wm + i * 16 + g * 4 + r;
        int b = m >> 10, sidx = m & 1023;
        float val = acc[i][j][r] + bsv;
        if (proj < 2) {
          float2 cssn = *(const float2*)&tab[(sidx * 32 + kidx) * 2];
          float p = __shfl_xor(val, 1);
          val = (val * cssn.x + sgn * (p * cssn.y)) * qs;
        }
        outp[((size_t)(b * 12 + hh) * 1024 + sidx) * 64 + d] = val;
      }
    }
  }
}

// ---------------------------------------------------------------------------
// Output projection (MFMA): out = A(8192x768) @ Wo + bo, A given as hi/lo bf16.
// ---------------------------------------------------------------------------
__global__ __launch_bounds__(256) void proj_mfma_kernel(
    const unsigned short* __restrict__ ah_, const unsigned short* __restrict__ al_,
    const unsigned short* __restrict__ wh_, const unsigned short* __restrict__ wl_,
    const float* __restrict__ bo, float* __restrict__ out) {
  __shared__ __align__(16) short sAh[4096], sAl[4096], sBh[4096], sBl[4096];
  const int t  = threadIdx.x;
  const int m0 = blockIdx.x * 128;
  const int n0 = blockIdx.y * 128;

  GEMM_MAIN_LOOP(ah_, al_, wh_, wl_, m0, n0)

#pragma unroll
  for (int j = 0; j < 4; ++j) {
    int n = n0 + wn + j * 16 + lm;
    float bsv = bo[n];
#pragma unroll
    for (int i = 0; i < 4; ++i) {
#pragma unroll
      for (int r = 0; r < 4; ++r) {
        int m = m0 + wm + i * 16 + g * 4 + r;
        out[(size_t)m * 768 + n] = acc[i][j][r] + bsv;
      }
    }
  }
}

// ---------------------------------------------------------------------------
// Flash attention (fp32), one block = one (b,h) x 64 q-rows, 16 K/V tiles.
// bfmode=1: epilogue writes hi/lo bf16 [B,S,768]; else fp32 [B,S,768].
// ---------------------------------------------------------------------------
__global__ __launch_bounds__(256) void attn_kernel(
    const float* __restrict__ qws, const float* __restrict__ kws,
    const float* __restrict__ vws, float* __restrict__ owsf,
    unsigned short* __restrict__ oh, unsigned short* __restrict__ ol,
    int bfmode) {
  __shared__ float qs[64][68];
  __shared__ float ks[64][68];   // K tile, then P tile
  __shared__ float vs[64][68];
  const int t  = threadIdx.x;
  const int qc = blockIdx.x & 15;
  const int bh = blockIdx.x >> 4;
  const int tx = t & 15, ty = t >> 4;

  const float* qbase = qws + ((size_t)bh * 1024 + qc * 64) * 64;
#pragma unroll
  for (int r = 0; r < 4; ++r) {
    int e = t + 256 * r;
    int row = e >> 4, dq = e & 15;
    *(float4*)&qs[row][dq*4] = *(const float4*)&qbase[row * 64 + dq * 4];
  }

  float m_run[4], l_run[4], o[4][4];
#pragma unroll
  for (int i = 0; i < 4; ++i) {
    m_run[i] = -1e30f; l_run[i] = 0.f;
#pragma unroll
    for (int j = 0; j < 4; ++j) o[i][j] = 0.f;
  }

  for (int kt = 0; kt < 16; ++kt) {
    __syncthreads();
    const float* kb = kws + ((size_t)bh * 1024 + kt * 64) * 64;
    const float* vb = vws + ((size_t)bh * 1024 + kt * 64) * 64;
#pragma unroll
    for (int r = 0; r < 4; ++r) {
      int e = t + 256 * r;
      int row = e >> 4, dq = e & 15;
      *(float4*)&ks[row][dq*4] = *(const float4*)&kb[row * 64 + dq * 4];
      *(float4*)&vs[row][dq*4] = *(const float4*)&vb[row * 64 + dq * 4];
    }
    __syncthreads();

    float sacc[4][4];
#pragma unroll
    for (int i = 0; i < 4; ++i)
#pragma unroll
      for (int j = 0; j < 4; ++j) sacc[i][j] = 0.f;
#pragma unroll
    for (int d0 = 0; d0 < 64; d0 += 4) {
      float4 qv[4], kv[4];
#pragma unroll
      for (int i = 0; i < 4; ++i) qv[i] = *(float4*)&qs[ty*4+i][d0];
#pragma unroll
      for (int j = 0; j < 4; ++j) kv[j] = *(float4*)&ks[tx*4+j][d0];
#pragma unroll
      for (int i = 0; i < 4; ++i)
#pragma unroll
        for (int j = 0; j < 4; ++j)
          sacc[i][j] += qv[i].x*kv[j].x + qv[i].y*kv[j].y +
                        qv[i].z*kv[j].z + qv[i].w*kv[j].w;
    }
    __syncthreads();

#pragma unroll
    for (int i = 0; i < 4; ++i) {
      float mt = fmaxf(fmaxf(sacc[i][0], sacc[i][1]),
                       fmaxf(sacc[i][2], sacc[i][3]));
#pragma unroll
      for (int off = 1; off < 16; off <<= 1)
        mt = fmaxf(mt, __shfl_xor(mt, off));
      float mn   = fmaxf(m_run[i], mt);
      float corr = __expf(m_run[i] - mn);
      m_run[i] = mn;
      float p0 = __expf(sacc[i][0] - mn);
      float p1 = __expf(sacc[i][1] - mn);
      float p2 = __expf(sacc[i][2] - mn);
      float p3 = __expf(sacc[i][3] - mn);
      float ls = p0 + p1 + p2 + p3;
#pragma unroll
      for (int off = 1; off < 16; off <<= 1)
        ls += __shfl_xor(ls, off);
      l_run[i] = l_run[i] * corr + ls;
#pragma unroll
      for (int j = 0; j < 4; ++j) o[i][j] *= corr;
      *(float4*)&ks[ty*4+i][tx*4] = make_float4(p0, p1, p2, p3);
    }
    __syncthreads();

#pragma unroll
    for (int j0 = 0; j0 < 64; j0 += 4) {
      float4 pv4[4], vv4[4];
#pragma unroll
      for (int i = 0; i < 4; ++i)  pv4[i] = *(float4*)&ks[ty*4+i][j0];
#pragma unroll
      for (int jj = 0; jj < 4; ++jj) vv4[jj] = *(float4*)&vs[j0+jj][tx*4];
#pragma unroll
      for (int i = 0; i < 4; ++i) {
        float pj[4] = {pv4[i].x, pv4[i].y, pv4[i].z, pv4[i].w};
#pragma unroll
        for (int jj = 0; jj < 4; ++jj) {
          o[i][0] += pj[jj] * vv4[jj].x;
          o[i][1] += pj[jj] * vv4[jj].y;
          o[i][2] += pj[jj] * vv4[jj].z;
          o[i][3] += pj[jj] * vv4[jj].w;
        }
      }
    }
  }

  const int b = bh / 12, h = bh % 12;
#pragma unroll
  for (int i = 0; i < 4; ++i) {
    int s = qc * 64 + ty * 4 + i;
    float inv = 1.f / l_run[i];
    size_t off = ((size_t)(b * 1024 + s)) * 768 + h * 64 + tx * 4;
    if (bfmode) {
      ushort4 hv, lv;
      float f0 = o[i][0]*inv, f1 = o[i][1]*inv, f2 = o[i][2]*inv, f3 = o[i][3]*inv;
      bsplit(f0, hv.x, lv.x); bsplit(f1, hv.y, lv.y);
      bsplit(f2, hv.z, lv.z); bsplit(f3, hv.w, lv.w);
      *(ushort4*)&oh[off] = hv;
      *(ushort4*)&ol[off] = lv;
    } else {
      *(float4*)&owsf[off] =
          make_float4(o[i][0]*inv, o[i][1]*inv, o[i][2]*inv, o[i][3]*inv);
    }
  }
}

// ---------------------------------------------------------------------------
// Fallback fp32 GEMMs (round-1 verified) in case ws_size is too small.
// ---------------------------------------------------------------------------
__global__ __launch_bounds__(256) void qkv_f32_kernel(
    const float* __restrict__ x,
    const float* __restrict__ Wq, const float* __restrict__ bq,
    const float* __restrict__ Wk, const float* __restrict__ bk,
    const float* __restrict__ Wv, const float* __restrict__ bv,
    const float* __restrict__ tab,
    float* __restrict__ qws, float* __restrict__ kws, float* __restrict__ vws) {
  __shared__ float As[16][132];
  __shared__ float Bs[16][132];
  const int t  = threadIdx.x;
  const int m0 = blockIdx.x * 128;
  const int n0 = blockIdx.y * 128;
  const int proj = n0 / 768;
  const int col0 = n0 % 768;
  const float* W    = (proj == 0) ? Wq : (proj == 1) ? Wk : Wv;
  const float* bias = (proj == 0) ? bq : (proj == 1) ? bk : bv;
  const int ty = t >> 4, tx = t & 15;

  float acc[8][8];
#pragma unroll
  for (int i = 0; i < 8; ++i)
#pragma unroll
    for (int j = 0; j < 8; ++j) acc[i][j] = 0.f;

  for (int k0 = 0; k0 < 768; k0 += 16) {
    __syncthreads();
#pragma unroll
    for (int r2 = 0; r2 < 2; ++r2) {
      int q  = t + r2 * 256;
      int mi = q >> 2, kq = q & 3;
      float4 f = *(const float4*)(x + (size_t)(m0 + mi) * 768 + k0 + kq * 4);
      As[kq*4+0][mi] = f.x; As[kq*4+1][mi] = f.y;
      As[kq*4+2][mi] = f.z; As[kq*4+3][mi] = f.w;
      int kk = q >> 5, nq = q & 31;
      *(float4*)&Bs[kk][nq*4] =
          *(const float4*)(W + (size_t)(k0 + kk) * 768 + col0 + nq * 4);
    }
    __syncthreads();
#pragma unroll
    for (int kk = 0; kk < 16; ++kk) {
      float a[8], b[8];
      *(float4*)&a[0] = *(const float4*)&As[kk][ty*8];
      *(float4*)&a[4] = *(const float4*)&As[kk][ty*8+4];
      *(float4*)&b[0] = *(const float4*)&Bs[kk][tx*8];
      *(float4*)&b[4] = *(const float4*)&Bs[kk][tx*8+4];
#pragma unroll
      for (int i = 0; i < 8; ++i)
#pragma unroll
        for (int j = 0; j < 8; ++j) acc[i][j] += a[i] * b[j];
    }
  }

  const int colb = col0 + tx * 8;
  const int h  = colb >> 6;
  const int d0 = colb & 63;
  float bv8[8];
#pragma unroll
  for (int j = 0; j < 8; ++j) bv8[j] = bias[colb + j];
  float* outp = (proj == 0) ? qws : (proj == 1) ? kws : vws;

#pragma unroll
  for (int i = 0; i < 8; ++i) {
    int m = m0 + ty * 8 + i;
    int b = m >> 10, s = m & 1023;
    float v8[8];
#pragma unroll
    for (int j = 0; j < 8; ++j) v8[j] = acc[i][j] + bv8[j];
    if (proj < 2) {
#pragma unroll
      for (int jp = 0; jp < 8; jp += 2) {
        int d    = d0 + jp;
        int kidx = (d < 32) ? (d >> 1) : (16 + ((d - 32) >> 1));
        float cs = tab[2*(s*32 + kidx)];
        float sn = tab[2*(s*32 + kidx) + 1];
        float e = v8[jp], o = v8[jp+1];
        v8[jp]   = e * cs - o * sn;
        v8[jp+1] = e * sn + o * cs;
      }
      if (proj == 0) {
#pragma unroll
        for (int j = 0; j < 8; ++j) v8[j] *= 0.125f;
      }
    }
    size_t off = ((size_t)(b * 12 + h) * 1024 + s) * 64 + d0;
    *(float4*)&outp[off]     = make_float4(v8[0], v8[1], v8[2], v8[3]);
    *(float4*)&outp[off + 4] = make_float4(v8[4], v8[5], v8[6], v8[7]);
  }
}

__global__ __launch_bounds__(256) void proj_f32_kernel(
    const float* __restrict__ A, const float* __restrict__ W,
    const float* __restrict__ bias, float* __restrict__ C) {
  __shared__ float As[16][132];
  __shared__ float Bs[16][132];
  const int t  = threadIdx.x;
  const int m0 = blockIdx.x * 128;
  const int n0 = blockIdx.y * 128;
  const int ty = t >> 4, tx = t & 15;

  float acc[8][8];
#pragma unroll
  for (int i = 0; i < 8; ++i)
#pragma unroll
    for (int j = 0; j < 8; ++j) acc[i][j] = 0.f;

  for (int k0 = 0; k0 < 768; k0 += 16) {
    __syncthreads();
#pragma unroll
    for (int r2 = 0; r2 < 2; ++r2) {
      int q  = t + r2 * 256;
      int mi = q >> 2, kq = q & 3;
      float4 f = *(const float4*)(A + (size_t)(m0 + mi) * 768 + k0 + kq * 4);
      As[kq*4+0][mi] = f.x; As[kq*4+1][mi] = f.y;
      As[kq*4+2][mi] = f.z; As[kq*4+3][mi] = f.w;
      int kk = q >> 5, nq = q & 31;
      *(float4*)&Bs[kk][nq*4] =
          *(const float4*)(W + (size_t)(k0 + kk) * 768 + n0 + nq * 4);
    }
    __syncthreads();
#pragma unroll
    for (int kk = 0; kk < 16; ++kk) {
      float a[8], b[8];
      *(float4*)&a[0] = *(const float4*)&As[kk][ty*8];
      *(float4*)&a[4] = *(const float4*)&As[kk][ty*8+4];
      *(float4*)&b[0] = *(const float4*)&Bs[kk][tx*8];
      *(float4*)&b[4] = *(const float4*)&Bs[kk][tx*8+4];
#pragma unroll
      for (int i = 0; i < 8; ++i)
#pragma unroll
        for (int j = 0; j < 8; ++j) acc[i][j] += a[i] * b[j];
    }
  }

  float bv8[8];
#pragma unroll
  for (int j = 0; j < 8; ++j) bv8[j] = bias[n0 + tx*8 + j];
#pragma unroll
  for (int i = 0; i < 8; ++i) {
    int m = m0 + ty * 8 + i;
    float v8[8];
#pragma unroll
    for (int j = 0; j < 8; ++j) v8[j] = acc[i][j] + bv8[j];
    *(float4*)&C[(size_t)m * 768 + n0 + tx*8]     =
        make_float4(v8[0], v8[1], v8[2], v8[3]);
    *(float4*)&C[(size_t)m * 768 + n0 + tx*8 + 4] =
        make_float4(v8[4], v8[5], v8[6], v8[7]);
  }
}

// ---------------------------------------------------------------------------
extern "C" void kernel_launch(void* const* d_in, const int* in_sizes, int n_in,
                              void* d_out, int out_size, void* d_ws, size_t ws_size,
                              hipStream_t stream) {
  const float* x  = (const float*)d_in[0];
  const float* Wq = (const float*)d_in[1];
  const float* bq = (const float*)d_in[2];
  const float* Wk = (const float*)d_in[3];
  const float* bk = (const float*)d_in[4];
  const float* Wv = (const float*)d_in[5];
  const float* bv = (const float*)d_in[6];
  const float* Wo = (const float*)d_in[7];
  const float* bo = (const float*)d_in[8];
  float* out = (float*)d_out;

  char* w = (char*)d_ws;
  const size_t NEED = 110362624ull;

  if (ws_size >= NEED) {
    float* tab          = (float*)(w);                     // 262144 B
    float* qf           = (float*)(w + 262144);            // 25165824 B
    float* kf           = (float*)(w + 25427968);
    float* vf           = (float*)(w + 50593792);
    unsigned short* wth = (unsigned short*)(w + 75759616); // 3538944 B
    unsigned short* wtl = (unsigned short*)(w + 79298560);
    unsigned short* woh = (unsigned short*)(w + 82837504); // 1179648 B
    unsigned short* wol = (unsigned short*)(w + 84017152);
    unsigned short* xh  = (unsigned short*)(w + 85196800); // 12582912 B (-> aws hi)
    unsigned short* xl  = (unsigned short*)(w + 97779712); // 12582912 B (-> aws lo)

    rope_tab_kernel<<<dim3(128), dim3(256), 0, stream>>>(tab);
    xconv_kernel<<<dim3(6144), dim3(256), 0, stream>>>(x, xh, xl);
    wconv_kernel<<<dim3(24, 24, 4), dim3(256), 0, stream>>>(
        Wq, Wk, Wv, Wo, wth, wtl, woh, wol);
    qkv_mfma_kernel<<<dim3(64, 18), dim3(256), 0, stream>>>(
        xh, xl, wth, wtl, bq, bk, bv, tab, qf, kf, vf);
    // attn reuses xh/xl as its hi/lo output (x no longer needed)
    attn_kernel<<<dim3(1536), dim3(256), 0, stream>>>(
        qf, kf, vf, qf /*unused*/, xh, xl, 1);
    proj_mfma_kernel<<<dim3(64, 6), dim3(256), 0, stream>>>(
        xh, xl, woh, wol, bo, out);
  } else {
    // fp32 fallback (fits in 101 MB)
    float* tab = (float*)(w);
    float* qf  = (float*)(w + 262144);
    float* kf  = (float*)(w + 25427968);
    float* vf  = (float*)(w + 50593792);
    float* aws = (float*)(w + 75759616);

    rope_tab_kernel<<<dim3(128), dim3(256), 0, stream>>>(tab);
    qkv_f32_kernel<<<dim3(64, 18), dim3(256), 0, stream>>>(
        x, Wq, bq, Wk, bk, Wv, bv, tab, qf, kf, vf);
    attn_kernel<<<dim3(1536), dim3(256), 0, stream>>>(
        qf, kf, vf, aws, (unsigned short*)aws, (unsigned short*)aws, 0);
    proj_f32_kernel<<<dim3(64, 6), dim3(256), 0, stream>>>(aws, Wo, bo, out);
  }
}

// Round 3
// 572.261 us; speedup vs baseline: 2.0256x; 1.3965x over previous
//
#include <hip/hip_runtime.h>
#include <hip/hip_bf16.h>
#include <math.h>

typedef __attribute__((ext_vector_type(8))) short short8;
typedef __attribute__((ext_vector_type(4))) float floatx4;
typedef const unsigned int __attribute__((address_space(1))) as1_cu32;
typedef unsigned int __attribute__((address_space(3))) as3_u32;

// ---------------- bf16 split helpers ----------------
__device__ __forceinline__ unsigned short bfh(float x) {
  union { __hip_bfloat16 b; unsigned short u; } c;
  c.b = __float2bfloat16(x); return c.u;
}
__device__ __forceinline__ float bf2f(unsigned short u) {
  union { unsigned u; float f; } a; a.u = ((unsigned)u) << 16; return a.f;
}
__device__ __forceinline__ void bsplit(float x, unsigned short& h, unsigned short& l) {
  h = bfh(x); l = bfh(x - bf2f(h));
}

// ---------------------------------------------------------------------------
// RoPE table: tab[s][k2][2] ; k2<16 -> row-angle pair k2, k2>=16 -> col-angle
// ---------------------------------------------------------------------------
__global__ void rope_tab_kernel(float* __restrict__ tab) {
  int idx = blockIdx.x * 256 + threadIdx.x;     // 0..32767
  if (idx >= 32768) return;
  int s  = idx >> 5, k2 = idx & 31;
  int r  = s >> 5,  c  = s & 31;
  int j  = k2 & 15;
  float f   = expf(-(float)j * (9.210340371976184f / 16.0f)); // 10000^(-j/16)
  float pos = (k2 < 16) ? (float)r : (float)c;
  float a   = pos * f;
  tab[2*idx]   = cosf(a);
  tab[2*idx+1] = sinf(a);
}

// ---------------------------------------------------------------------------
// Convert x (f32) -> hi/lo bf16, row-major [M][768]
// ---------------------------------------------------------------------------
__global__ __launch_bounds__(256) void xconv_kernel(
    const float* __restrict__ x, unsigned short* __restrict__ xh,
    unsigned short* __restrict__ xl) {
  int i = (blockIdx.x * 256 + threadIdx.x) * 4;
  float4 f = *(const float4*)&x[i];
  ushort4 h, l;
  bsplit(f.x, h.x, l.x); bsplit(f.y, h.y, l.y);
  bsplit(f.z, h.z, l.z); bsplit(f.w, h.w, l.w);
  *(ushort4*)&xh[i] = h;
  *(ushort4*)&xl[i] = l;
}

// ---------------------------------------------------------------------------
// Convert+transpose W [K=768][N=768] f32 -> Wt hi/lo [N][K] bf16.
// z = 0,1,2 -> Wq,Wk,Wv packed into wth/wtl rows z*768.. ; z=3 -> Wo.
// ---------------------------------------------------------------------------
__global__ __launch_bounds__(256) void wconv_kernel(
    const float* __restrict__ Wq, const float* __restrict__ Wk,
    const float* __restrict__ Wv, const float* __restrict__ Wo,
    unsigned short* __restrict__ wth, unsigned short* __restrict__ wtl,
    unsigned short* __restrict__ woh, unsigned short* __restrict__ wol) {
  __shared__ float tile[32][33];
  int z = blockIdx.z;
  const float* src = (z == 0) ? Wq : (z == 1) ? Wk : (z == 2) ? Wv : Wo;
  unsigned short* dh = (z < 3) ? wth + (size_t)z * 768 * 768 : woh;
  unsigned short* dl = (z < 3) ? wtl + (size_t)z * 768 * 768 : wol;
  int k0 = blockIdx.x * 32, n0 = blockIdx.y * 32;
  int tx = threadIdx.x & 31, ty = threadIdx.x >> 5;   // ty 0..7
#pragma unroll
  for (int r = 0; r < 4; ++r)
    tile[ty + r * 8][tx] = src[(size_t)(k0 + ty + r * 8) * 768 + n0 + tx];
  __syncthreads();
#pragma unroll
  for (int r = 0; r < 4; ++r) {
    int n = n0 + ty + r * 8;
    float v = tile[tx][ty + r * 8];
    unsigned short h, l; bsplit(v, h, l);
    dh[(size_t)n * 768 + k0 + tx] = h;
    dl[(size_t)n * 768 + k0 + tx] = l;
  }
}

// ---------------------------------------------------------------------------
// MFMA GEMM core (128x128 tile, BK=32, 4 waves, bf16x3) — verified round 2.
// ---------------------------------------------------------------------------
__device__ __forceinline__ void stage_tile(const unsigned short* __restrict__ src,
                                           int row0, int k0, short* lds, int t) {
  int l  = t & 63;
  int wb = t & 192;
#pragma unroll
  for (int r = 0; r < 2; ++r) {
    int cbase = r * 256 + wb;
    int c = cbase + l;
    int m = c >> 2, s = c & 3;
    int g = s ^ (m & 3);
    const unsigned short* gp = src + (size_t)(row0 + m) * 768 + k0 + g * 8;
    __builtin_amdgcn_global_load_lds((as1_cu32*)(const void*)gp,
                                     (as3_u32*)(void*)(lds + cbase * 8),
                                     16, 0, 0);
  }
}

#define GEMM_MAIN_LOOP(Ah, Al, Bh, Bl, m0, n0)                                   \
  floatx4 acc[4][4];                                                             \
  _Pragma("unroll") for (int i = 0; i < 4; ++i)                                  \
      _Pragma("unroll") for (int j = 0; j < 4; ++j)                              \
          acc[i][j] = (floatx4){0.f, 0.f, 0.f, 0.f};                             \
  const int l  = t & 63;                                                         \
  const int lm = l & 15, g = l >> 4;                                             \
  const int wm = ((t >> 7) & 1) * 64, wn = ((t >> 6) & 1) * 64;                  \
  const int sl = g ^ (lm & 3);                                                   \
  for (int k0 = 0; k0 < 768; k0 += 32) {                                         \
    __syncthreads();                                                             \
    stage_tile(Ah, m0, k0, sAh, t);                                              \
    stage_tile(Al, m0, k0, sAl, t);                                              \
    stage_tile(Bh, n0, k0, sBh, t);                                              \
    stage_tile(Bl, n0, k0, sBl, t);                                              \
    __syncthreads();                                                             \
    short8 ah[4], al[4];                                                         \
    _Pragma("unroll") for (int i = 0; i < 4; ++i) {                              \
      int ra = wm + i * 16 + lm;                                                 \
      ah[i] = *(const short8*)&sAh[ra * 32 + sl * 8];                            \
      al[i] = *(const short8*)&sAl[ra * 32 + sl * 8];                            \
    }                                                                            \
    _Pragma("unroll") for (int j = 0; j < 4; ++j) {                              \
      int rb = wn + j * 16 + lm;                                                 \
      short8 bh = *(const short8*)&sBh[rb * 32 + sl * 8];                        \
      short8 bl = *(const short8*)&sBl[rb * 32 + sl * 8];                        \
      _Pragma("unroll") for (int i = 0; i < 4; ++i) {                            \
        acc[i][j] = __builtin_amdgcn_mfma_f32_16x16x32_bf16(ah[i], bh, acc[i][j], 0, 0, 0); \
        acc[i][j] = __builtin_amdgcn_mfma_f32_16x16x32_bf16(ah[i], bl, acc[i][j], 0, 0, 0); \
        acc[i][j] = __builtin_amdgcn_mfma_f32_16x16x32_bf16(al[i], bh, acc[i][j], 0, 0, 0); \
      }                                                                          \
    }                                                                            \
  }

// ---------------------------------------------------------------------------
// QKV projection (MFMA). Epilogue: bias + 2D RoPE + 1/8 into q; emits
// q,k hi/lo bf16 [B,H,S,64] and V TRANSPOSED hi/lo [B,H,64,S].
// ---------------------------------------------------------------------------
__global__ __launch_bounds__(256) void qkv_mfma_kernel(
    const unsigned short* __restrict__ xh, const unsigned short* __restrict__ xl,
    const unsigned short* __restrict__ wth, const unsigned short* __restrict__ wtl,
    const float* __restrict__ bq, const float* __restrict__ bk,
    const float* __restrict__ bv, const float* __restrict__ tab,
    unsigned short* __restrict__ qhp, unsigned short* __restrict__ qlp,
    unsigned short* __restrict__ khp, unsigned short* __restrict__ klp,
    unsigned short* __restrict__ vth, unsigned short* __restrict__ vtl) {
  __shared__ __align__(16) short sAh[4096], sAl[4096], sBh[4096], sBl[4096];
  const int t  = threadIdx.x;
  const int m0 = blockIdx.x * 128;
  const int n0 = blockIdx.y * 128;

  GEMM_MAIN_LOOP(xh, xl, wth, wtl, m0, n0)

  const int proj = n0 / 768;
  const int col0 = n0 % 768;
  const float* bias = (proj == 0) ? bq : (proj == 1) ? bk : bv;
  const float qs = (proj == 0) ? 0.125f : 1.f;
  unsigned short* hdst = (proj == 0) ? qhp : khp;
  unsigned short* ldst = (proj == 0) ? qlp : klp;

  if (proj < 2) {
#pragma unroll
    for (int j = 0; j < 4; ++j) {
      int colf = col0 + wn + j * 16;
      int hh = colf >> 6;
      int d  = (colf & 63) + lm;
      float bsv = bias[colf + lm];
      int kidx = (d < 32) ? (d >> 1) : (16 + ((d - 32) >> 1));
      float sgn = (d & 1) ? 1.f : -1.f;
#pragma unroll
      for (int i = 0; i < 4; ++i) {
#pragma unroll
        for (int r = 0; r < 4; ++r) {
          int m = m0 + wm + i * 16 + g * 4 + r;
          int b = m >> 10, sidx = m & 1023;
          float val = acc[i][j][r] + bsv;
          float2 cssn = *(const float2*)&tab[(sidx * 32 + kidx) * 2];
          float p = __shfl_xor(val, 1);
          val = (val * cssn.x + sgn * (p * cssn.y)) * qs;
          unsigned short hv, lv; bsplit(val, hv, lv);
          unsigned hx = (unsigned)__shfl_xor((int)hv, 1);
          unsigned lx = (unsigned)__shfl_xor((int)lv, 1);
          size_t off = (((size_t)(b * 12 + hh)) * 1024 + sidx) * 64 + (d & ~1);
          if ((lm & 1) == 0)
            *(unsigned*)&hdst[off] = ((hx & 0xffffu) << 16) | (unsigned)hv;
          else
            *(unsigned*)&ldst[off] = (((unsigned)lv) << 16) | (lx & 0xffffu);
        }
      }
    }
  } else {
#pragma unroll
    for (int j = 0; j < 4; ++j) {
      int colf = col0 + wn + j * 16;
      int hh = colf >> 6;
      int d  = (colf & 63) + lm;
      float bsv = bias[colf + lm];
#pragma unroll
      for (int i = 0; i < 4; ++i) {
#pragma unroll
        for (int r = 0; r < 4; ++r) {
          int m = m0 + wm + i * 16 + g * 4 + r;
          int b = m >> 10, sidx = m & 1023;
          float val = acc[i][j][r] + bsv;
          unsigned short hv, lv; bsplit(val, hv, lv);
          size_t off = (((size_t)(b * 12 + hh)) * 64 + d) * 1024 + sidx;
          vth[off] = hv;
          vtl[off] = lv;
        }
      }
    }
  }
}

// ---------------------------------------------------------------------------
// MFMA flash attention. Block = 4 waves = one (b,h) x 128 q-rows; wave owns
// 32 q-rows. 16 K/V tiles of 64 keys; K rows [key][64d], VT rows [d][64key],
// XOR-slot swizzled (s = c ^ (row&7)), staged via global_load_lds(16B).
// P round-trips through per-wave LDS (hi/lo planes via even/odd lane packing).
// LDS = 16+16+32 = 64 KB.
// ---------------------------------------------------------------------------
__global__ __launch_bounds__(256) void attn_mfma_kernel(
    const unsigned short* __restrict__ qhp, const unsigned short* __restrict__ qlp,
    const unsigned short* __restrict__ khp, const unsigned short* __restrict__ klp,
    const unsigned short* __restrict__ vth, const unsigned short* __restrict__ vtl,
    unsigned short* __restrict__ oh, unsigned short* __restrict__ ol) {
  __shared__ __align__(16) short sK0[4096], sK1[4096], sVT0[4096], sVT1[4096];
  __shared__ __align__(16) short sP[2][4][2048];
  const int t  = threadIdx.x;
  const int wv = t >> 6, l = t & 63, lm = l & 15, g = l >> 4;
  const int bh  = blockIdx.x >> 3;
  const int qw0 = (blockIdx.x & 7) * 128 + wv * 32;

  // Q fragments -> regs (A-frag rows indexed by lm)
  short8 qfh[2][2], qfl[2][2];
#pragma unroll
  for (int i = 0; i < 2; ++i) {
    size_t base = ((size_t)bh * 1024 + qw0 + i * 16 + lm) * 64;
#pragma unroll
    for (int tt = 0; tt < 2; ++tt) {
      qfh[i][tt] = *(const short8*)&qhp[base + tt * 32 + g * 8];
      qfl[i][tt] = *(const short8*)&qlp[base + tt * 32 + g * 8];
    }
  }

  float mrun[2][4], lrun[2][4];
  floatx4 o[2][4];
#pragma unroll
  for (int i = 0; i < 2; ++i)
#pragma unroll
    for (int r = 0; r < 4; ++r) { mrun[i][r] = -1e30f; lrun[i][r] = 0.f; }
#pragma unroll
  for (int i = 0; i < 2; ++i)
#pragma unroll
    for (int jd = 0; jd < 4; ++jd) o[i][jd] = (floatx4){0.f, 0.f, 0.f, 0.f};

  short* stage_arr = (wv == 0) ? sK0 : (wv == 1) ? sK1 : (wv == 2) ? sVT0 : sVT1;
  const unsigned short* stage_src =
      (wv == 0) ? khp : (wv == 1) ? klp : (wv == 2) ? vth : vtl;
  const int isV = (wv >= 2);

#pragma unroll 1
  for (int kt = 0; kt < 16; ++kt) {
    __syncthreads();   // all waves done reading previous K/VT tiles
    // ---- stage this kt's tiles (each wave stages one 8KB plane) ----
#pragma unroll
    for (int qi = 0; qi < 8; ++qi) {
      int c = qi * 64 + l;
      int row = c >> 3, s = c & 7;
      int gs = s ^ (row & 7);
      const unsigned short* gp = isV
          ? stage_src + ((size_t)bh * 64 + row) * 1024 + kt * 64 + gs * 8
          : stage_src + ((size_t)bh * 1024 + kt * 64 + row) * 64 + gs * 8;
      __builtin_amdgcn_global_load_lds((as1_cu32*)(const void*)gp,
                                       (as3_u32*)(void*)(stage_arr + qi * 512),
                                       16, 0, 0);
    }
    __syncthreads();   // vmcnt(0) drained by compiler before barrier

    // ---- QK^T (3-term split) ----
    floatx4 sacc[2][4];
#pragma unroll
    for (int i = 0; i < 2; ++i)
#pragma unroll
      for (int j = 0; j < 4; ++j) sacc[i][j] = (floatx4){0.f, 0.f, 0.f, 0.f};
#pragma unroll
    for (int tt = 0; tt < 2; ++tt) {
#pragma unroll
      for (int j = 0; j < 4; ++j) {
        int row = j * 16 + lm;
        int so = ((4 * tt + g) ^ (row & 7)) * 8;
        short8 kfh = *(const short8*)&sK0[row * 64 + so];
        short8 kfl = *(const short8*)&sK1[row * 64 + so];
#pragma unroll
        for (int i = 0; i < 2; ++i) {
          sacc[i][j] = __builtin_amdgcn_mfma_f32_16x16x32_bf16(qfh[i][tt], kfh, sacc[i][j], 0, 0, 0);
          sacc[i][j] = __builtin_amdgcn_mfma_f32_16x16x32_bf16(qfh[i][tt], kfl, sacc[i][j], 0, 0, 0);
          sacc[i][j] = __builtin_amdgcn_mfma_f32_16x16x32_bf16(qfl[i][tt], kfh, sacc[i][j], 0, 0, 0);
        }
      }
    }

    // ---- online softmax + P write (hi plane: even lanes, lo: odd lanes) ----
#pragma unroll
    for (int i = 0; i < 2; ++i) {
#pragma unroll
      for (int r = 0; r < 4; ++r) {
        float s0 = sacc[i][0][r], s1 = sacc[i][1][r];
        float s2 = sacc[i][2][r], s3 = sacc[i][3][r];
        float mt = fmaxf(fmaxf(s0, s1), fmaxf(s2, s3));
#pragma unroll
        for (int of = 1; of < 16; of <<= 1) mt = fmaxf(mt, __shfl_xor(mt, of));
        float mn = fmaxf(mrun[i][r], mt);
        float corr = __expf(mrun[i][r] - mn);
        mrun[i][r] = mn;
        float p0 = __expf(s0 - mn), p1 = __expf(s1 - mn);
        float p2 = __expf(s2 - mn), p3 = __expf(s3 - mn);
        float ps = p0 + p1 + p2 + p3;
#pragma unroll
        for (int of = 1; of < 16; of <<= 1) ps += __shfl_xor(ps, of);
        lrun[i][r] = lrun[i][r] * corr + ps;
#pragma unroll
        for (int jd = 0; jd < 4; ++jd) o[i][jd][r] *= corr;
        int qrow = i * 16 + g * 4 + r;
        float pv_[4] = {p0, p1, p2, p3};
#pragma unroll
        for (int j = 0; j < 4; ++j) {
          unsigned short hv, lv; bsplit(pv_[j], hv, lv);
          unsigned hx = (unsigned)__shfl_xor((int)hv, 1);
          unsigned lx = (unsigned)__shfl_xor((int)lv, 1);
          int koff = qrow * 64 + j * 16 + (lm & ~1);
          if ((lm & 1) == 0)
            *(unsigned*)&sP[0][wv][koff] = ((hx & 0xffffu) << 16) | (unsigned)hv;
          else
            *(unsigned*)&sP[1][wv][koff] = (((unsigned)lv) << 16) | (lx & 0xffffu);
        }
      }
    }

    // ---- PV (3-term split): O += P * V  via  A=P rows(q), B=VT rows(d) ----
#pragma unroll
    for (int tt = 0; tt < 2; ++tt) {
      short8 pfh[2], pfl[2];
#pragma unroll
      for (int i = 0; i < 2; ++i) {
        int po = (i * 16 + lm) * 64 + tt * 32 + g * 8;
        pfh[i] = *(const short8*)&sP[0][wv][po];
        pfl[i] = *(const short8*)&sP[1][wv][po];
      }
#pragma unroll
      for (int jd = 0; jd < 4; ++jd) {
        int row = jd * 16 + lm;
        int so = ((4 * tt + g) ^ (row & 7)) * 8;
        short8 vfh = *(const short8*)&sVT0[row * 64 + so];
        short8 vfl = *(const short8*)&sVT1[row * 64 + so];
#pragma unroll
        for (int i = 0; i < 2; ++i) {
          o[i][jd] = __builtin_amdgcn_mfma_f32_16x16x32_bf16(pfh[i], vfh, o[i][jd], 0, 0, 0);
          o[i][jd] = __builtin_amdgcn_mfma_f32_16x16x32_bf16(pfh[i], vfl, o[i][jd], 0, 0, 0);
          o[i][jd] = __builtin_amdgcn_mfma_f32_16x16x32_bf16(pfl[i], vfh, o[i][jd], 0, 0, 0);
        }
      }
    }
  }

  // ---- epilogue: normalize, split hi/lo, write [B,S,768] bf16 planes ----
  const int b = bh / 12, h = bh % 12;
#pragma unroll
  for (int i = 0; i < 2; ++i) {
#pragma unroll
    for (int r = 0; r < 4; ++r) {
      int sq = qw0 + i * 16 + g * 4 + r;
      float inv = 1.f / lrun[i][r];
#pragma unroll
      for (int jd = 0; jd < 4; ++jd) {
        int d = jd * 16 + lm;
        float val = o[i][jd][r] * inv;
        unsigned short hv, lv; bsplit(val, hv, lv);
        unsigned hx = (unsigned)__shfl_xor((int)hv, 1);
        unsigned lx = (unsigned)__shfl_xor((int)lv, 1);
        size_t off = ((size_t)(b * 1024) + sq) * 768 + h * 64 + (d & ~1);
        if ((lm & 1) == 0)
          *(unsigned*)&oh[off] = ((hx & 0xffffu) << 16) | (unsigned)hv;
        else
          *(unsigned*)&ol[off] = (((unsigned)lv) << 16) | (lx & 0xffffu);
      }
    }
  }
}

// ---------------------------------------------------------------------------
// Output projection (MFMA) — verified round 2.
// ---------------------------------------------------------------------------
__global__ __launch_bounds__(256) void proj_mfma_kernel(
    const unsigned short* __restrict__ ah_, const unsigned short* __restrict__ al_,
    const unsigned short* __restrict__ wh_, const unsigned short* __restrict__ wl_,
    const float* __restrict__ bo, float* __restrict__ out) {
  __shared__ __align__(16) short sAh[4096], sAl[4096], sBh[4096], sBl[4096];
  const int t  = threadIdx.x;
  const int m0 = blockIdx.x * 128;
  const int n0 = blockIdx.y * 128;

  GEMM_MAIN_LOOP(ah_, al_, wh_, wl_, m0, n0)

#pragma unroll
  for (int j = 0; j < 4; ++j) {
    int n = n0 + wn + j * 16 + lm;
    float bsv = bo[n];
#pragma unroll
    for (int i = 0; i < 4; ++i) {
#pragma unroll
      for (int r = 0; r < 4; ++r) {
        int m = m0 + wm + i * 16 + g * 4 + r;
        out[(size_t)m * 768 + n] = acc[i][j][r] + bsv;
      }
    }
  }
}

// ---------------------------------------------------------------------------
extern "C" void kernel_launch(void* const* d_in, const int* in_sizes, int n_in,
                              void* d_out, int out_size, void* d_ws, size_t ws_size,
                              hipStream_t stream) {
  const float* x  = (const float*)d_in[0];
  const float* Wq = (const float*)d_in[1];
  const float* bq = (const float*)d_in[2];
  const float* Wk = (const float*)d_in[3];
  const float* bk = (const float*)d_in[4];
  const float* Wv = (const float*)d_in[5];
  const float* bv = (const float*)d_in[6];
  const float* Wo = (const float*)d_in[7];
  const float* bo = (const float*)d_in[8];
  float* out = (float*)d_out;

  char* w = (char*)d_ws;
  // layout (110,362,624 B total — same as round 2's verified NEED)
  float* tab          = (float*)(w);                      // 262144
  unsigned short* wth = (unsigned short*)(w + 262144);    // 3538944
  unsigned short* wtl = (unsigned short*)(w + 3801088);   // 3538944
  unsigned short* woh = (unsigned short*)(w + 7340032);   // 1179648
  unsigned short* wol = (unsigned short*)(w + 8519680);   // 1179648
  unsigned short* xh  = (unsigned short*)(w + 9699328);   // 12582912 (reused: attn out hi)
  unsigned short* xl  = (unsigned short*)(w + 22282240);  // 12582912 (reused: attn out lo)
  unsigned short* qh  = (unsigned short*)(w + 34865152);  // 12582912
  unsigned short* ql  = (unsigned short*)(w + 47448064);
  unsigned short* kh  = (unsigned short*)(w + 60030976);
  unsigned short* kl  = (unsigned short*)(w + 72613888);
  unsigned short* vth = (unsigned short*)(w + 85196800);
  unsigned short* vtl = (unsigned short*)(w + 97779712);  // end 110362624

  rope_tab_kernel<<<dim3(128), dim3(256), 0, stream>>>(tab);
  xconv_kernel<<<dim3(6144), dim3(256), 0, stream>>>(x, xh, xl);
  wconv_kernel<<<dim3(24, 24, 4), dim3(256), 0, stream>>>(
      Wq, Wk, Wv, Wo, wth, wtl, woh, wol);
  qkv_mfma_kernel<<<dim3(64, 18), dim3(256), 0, stream>>>(
      xh, xl, wth, wtl, bq, bk, bv, tab, qh, ql, kh, kl, vth, vtl);
  // attn writes its hi/lo output into xh/xl (x no longer needed)
  attn_mfma_kernel<<<dim3(768), dim3(256), 0, stream>>>(
      qh, ql, kh, kl, vth, vtl, xh, xl);
  proj_mfma_kernel<<<dim3(64, 6), dim3(256), 0, stream>>>(
      xh, xl, woh, wol, bo, out);
}

// Round 5
// 389.209 us; speedup vs baseline: 2.9783x; 1.4703x over previous
//
#include <hip/hip_runtime.h>
#include <hip/hip_bf16.h>
#include <math.h>

typedef __attribute__((ext_vector_type(8))) short short8;
typedef __attribute__((ext_vector_type(4))) float floatx4;
typedef const unsigned int __attribute__((address_space(1))) as1_cu32;
typedef unsigned int __attribute__((address_space(3))) as3_u32;

// ---------------- bf16 split helpers ----------------
__device__ __forceinline__ unsigned short bfh(float x) {
  union { __hip_bfloat16 b; unsigned short u; } c;
  c.b = __float2bfloat16(x); return c.u;
}
__device__ __forceinline__ float bf2f(unsigned short u) {
  union { unsigned u; float f; } a; a.u = ((unsigned)u) << 16; return a.f;
}
__device__ __forceinline__ void bsplit(float x, unsigned short& h, unsigned short& l) {
  h = bfh(x); l = bfh(x - bf2f(h));
}

// ---------------------------------------------------------------------------
// RoPE table
// ---------------------------------------------------------------------------
__global__ void rope_tab_kernel(float* __restrict__ tab) {
  int idx = blockIdx.x * 256 + threadIdx.x;
  if (idx >= 32768) return;
  int s  = idx >> 5, k2 = idx & 31;
  int r  = s >> 5,  c  = s & 31;
  int j  = k2 & 15;
  float f   = expf(-(float)j * (9.210340371976184f / 16.0f));
  float pos = (k2 < 16) ? (float)r : (float)c;
  float a   = pos * f;
  tab[2*idx]   = cosf(a);
  tab[2*idx+1] = sinf(a);
}

// ---------------------------------------------------------------------------
// x -> hi/lo bf16
// ---------------------------------------------------------------------------
__global__ __launch_bounds__(256) void xconv_kernel(
    const float* __restrict__ x, unsigned short* __restrict__ xh,
    unsigned short* __restrict__ xl) {
  int i = (blockIdx.x * 256 + threadIdx.x) * 4;
  float4 f = *(const float4*)&x[i];
  ushort4 h, l;
  bsplit(f.x, h.x, l.x); bsplit(f.y, h.y, l.y);
  bsplit(f.z, h.z, l.z); bsplit(f.w, h.w, l.w);
  *(ushort4*)&xh[i] = h;
  *(ushort4*)&xl[i] = l;
}

// ---------------------------------------------------------------------------
// W -> Wt hi/lo [N][K]
// ---------------------------------------------------------------------------
__global__ __launch_bounds__(256) void wconv_kernel(
    const float* __restrict__ Wq, const float* __restrict__ Wk,
    const float* __restrict__ Wv, const float* __restrict__ Wo,
    unsigned short* __restrict__ wth, unsigned short* __restrict__ wtl,
    unsigned short* __restrict__ woh, unsigned short* __restrict__ wol) {
  __shared__ float tile[32][33];
  int z = blockIdx.z;
  const float* src = (z == 0) ? Wq : (z == 1) ? Wk : (z == 2) ? Wv : Wo;
  unsigned short* dh = (z < 3) ? wth + (size_t)z * 768 * 768 : woh;
  unsigned short* dl = (z < 3) ? wtl + (size_t)z * 768 * 768 : wol;
  int k0 = blockIdx.x * 32, n0 = blockIdx.y * 32;
  int tx = threadIdx.x & 31, ty = threadIdx.x >> 5;
#pragma unroll
  for (int r = 0; r < 4; ++r)
    tile[ty + r * 8][tx] = src[(size_t)(k0 + ty + r * 8) * 768 + n0 + tx];
  __syncthreads();
#pragma unroll
  for (int r = 0; r < 4; ++r) {
    int n = n0 + ty + r * 8;
    float v = tile[tx][ty + r * 8];
    unsigned short h, l; bsplit(v, h, l);
    dh[(size_t)n * 768 + k0 + tx] = h;
    dl[(size_t)n * 768 + k0 + tx] = l;
  }
}

// ---------------------------------------------------------------------------
// MFMA GEMM core (128x128 tile, BK=32, 4 waves, bf16x3) — verified r2/r3.
// ---------------------------------------------------------------------------
__device__ __forceinline__ void stage_tile(const unsigned short* __restrict__ src,
                                           int row0, int k0, short* lds, int t) {
  int l  = t & 63;
  int wb = t & 192;
#pragma unroll
  for (int r = 0; r < 2; ++r) {
    int cbase = r * 256 + wb;
    int c = cbase + l;
    int m = c >> 2, s = c & 3;
    int g = s ^ (m & 3);
    const unsigned short* gp = src + (size_t)(row0 + m) * 768 + k0 + g * 8;
    __builtin_amdgcn_global_load_lds((as1_cu32*)(const void*)gp,
                                     (as3_u32*)(void*)(lds + cbase * 8),
                                     16, 0, 0);
  }
}

#define GEMM_MAIN_LOOP(Ah, Al, Bh, Bl, m0, n0)                                   \
  floatx4 acc[4][4];                                                             \
  _Pragma("unroll") for (int i = 0; i < 4; ++i)                                  \
      _Pragma("unroll") for (int j = 0; j < 4; ++j)                              \
          acc[i][j] = (floatx4){0.f, 0.f, 0.f, 0.f};                             \
  const int l  = t & 63;                                                         \
  const int lm = l & 15, g = l >> 4;                                             \
  const int wm = ((t >> 7) & 1) * 64, wn = ((t >> 6) & 1) * 64;                  \
  const int sl = g ^ (lm & 3);                                                   \
  for (int k0 = 0; k0 < 768; k0 += 32) {                                         \
    __syncthreads();                                                             \
    stage_tile(Ah, m0, k0, sAh, t);                                              \
    stage_tile(Al, m0, k0, sAl, t);                                              \
    stage_tile(Bh, n0, k0, sBh, t);                                              \
    stage_tile(Bl, n0, k0, sBl, t);                                              \
    __syncthreads();                                                             \
    short8 ah[4], al[4];                                                         \
    _Pragma("unroll") for (int i = 0; i < 4; ++i) {                              \
      int ra = wm + i * 16 + lm;                                                 \
      ah[i] = *(const short8*)&sAh[ra * 32 + sl * 8];                            \
      al[i] = *(const short8*)&sAl[ra * 32 + sl * 8];                            \
    }                                                                            \
    _Pragma("unroll") for (int j = 0; j < 4; ++j) {                              \
      int rb = wn + j * 16 + lm;                                                 \
      short8 bh = *(const short8*)&sBh[rb * 32 + sl * 8];                        \
      short8 bl = *(const short8*)&sBl[rb * 32 + sl * 8];                        \
      _Pragma("unroll") for (int i = 0; i < 4; ++i) {                            \
        acc[i][j] = __builtin_amdgcn_mfma_f32_16x16x32_bf16(ah[i], bh, acc[i][j], 0, 0, 0); \
        acc[i][j] = __builtin_amdgcn_mfma_f32_16x16x32_bf16(ah[i], bl, acc[i][j], 0, 0, 0); \
        acc[i][j] = __builtin_amdgcn_mfma_f32_16x16x32_bf16(al[i], bh, acc[i][j], 0, 0, 0); \
      }                                                                          \
    }                                                                            \
  }

// ---------------------------------------------------------------------------
// Q/K projection (MFMA): N cols 0..1535. RoPE epilogue, bf16 hi/lo out.
// ---------------------------------------------------------------------------
__global__ __launch_bounds__(256) void qk_mfma_kernel(
    const unsigned short* __restrict__ xh, const unsigned short* __restrict__ xl,
    const unsigned short* __restrict__ wth, const unsigned short* __restrict__ wtl,
    const float* __restrict__ bq, const float* __restrict__ bk,
    const float* __restrict__ tab,
    unsigned short* __restrict__ qhp, unsigned short* __restrict__ qlp,
    unsigned short* __restrict__ khp, unsigned short* __restrict__ klp) {
  __shared__ __align__(16) short sAh[4096], sAl[4096], sBh[4096], sBl[4096];
  const int t  = threadIdx.x;
  const int m0 = blockIdx.x * 128;
  const int n0 = blockIdx.y * 128;

  GEMM_MAIN_LOOP(xh, xl, wth, wtl, m0, n0)

  const int proj = n0 / 768;
  const int col0 = n0 % 768;
  const float* bias = (proj == 0) ? bq : bk;
  const float qs = (proj == 0) ? 0.125f : 1.f;
  unsigned short* hdst = (proj == 0) ? qhp : khp;
  unsigned short* ldst = (proj == 0) ? qlp : klp;

#pragma unroll
  for (int j = 0; j < 4; ++j) {
    int colf = col0 + wn + j * 16;
    int hh = colf >> 6;
    int d  = (colf & 63) + lm;
    float bsv = bias[colf + lm];
    int kidx = (d < 32) ? (d >> 1) : (16 + ((d - 32) >> 1));
    float sgn = (d & 1) ? 1.f : -1.f;
#pragma unroll
    for (int i = 0; i < 4; ++i) {
#pragma unroll
      for (int r = 0; r < 4; ++r) {
        int m = m0 + wm + i * 16 + g * 4 + r;
        int b = m >> 10, sidx = m & 1023;
        float val = acc[i][j][r] + bsv;
        float2 cssn = *(const float2*)&tab[(sidx * 32 + kidx) * 2];
        float p = __shfl_xor(val, 1);
        val = (val * cssn.x + sgn * (p * cssn.y)) * qs;
        unsigned short hv, lv; bsplit(val, hv, lv);
        unsigned hx = (unsigned)__shfl_xor((int)hv, 1);
        unsigned lx = (unsigned)__shfl_xor((int)lv, 1);
        size_t off = (((size_t)(b * 12 + hh)) * 1024 + sidx) * 64 + (d & ~1);
        if ((lm & 1) == 0)
          *(unsigned*)&hdst[off] = ((hx & 0xffffu) << 16) | (unsigned)hv;
        else
          *(unsigned*)&ldst[off] = (((unsigned)lv) << 16) | (lx & 0xffffu);
      }
    }
  }
}

// ---------------------------------------------------------------------------
// V projection (MFMA) with LDS-transposed, coalesced V^T output [B,H,64,S].
// XOR-chunk swizzle in the transpose tile (chunk ^= n&7) -> no bank storms.
// ---------------------------------------------------------------------------
__global__ __launch_bounds__(256) void v_mfma_kernel(
    const unsigned short* __restrict__ xh, const unsigned short* __restrict__ xl,
    const unsigned short* __restrict__ wvh, const unsigned short* __restrict__ wvl,
    const float* __restrict__ bv,
    unsigned short* __restrict__ vth, unsigned short* __restrict__ vtl) {
  __shared__ __align__(16) short smem[16384];
  short* sAh = smem;         short* sAl = smem + 4096;
  short* sBh = smem + 8192;  short* sBl = smem + 12288;
  const int t  = threadIdx.x;
  const int m0 = blockIdx.x * 128;
  const int n0 = blockIdx.y * 128;

  GEMM_MAIN_LOOP(xh, xl, wvh, wvl, m0, n0)

  // bias + split both planes into packed regs (frees acc)
  uint2 hpk[4][4], lpk[4][4];
#pragma unroll
  for (int j = 0; j < 4; ++j) {
    float bsv = bv[n0 + wn + j * 16 + lm];
#pragma unroll
    for (int i = 0; i < 4; ++i) {
      unsigned short hv[4], lv[4];
#pragma unroll
      for (int r = 0; r < 4; ++r) bsplit(acc[i][j][r] + bsv, hv[r], lv[r]);
      hpk[i][j] = make_uint2((unsigned)hv[0] | ((unsigned)hv[1] << 16),
                             (unsigned)hv[2] | ((unsigned)hv[3] << 16));
      lpk[i][j] = make_uint2((unsigned)lv[0] | ((unsigned)lv[1] << 16),
                             (unsigned)lv[2] | ((unsigned)lv[3] << 16));
    }
  }
  const int bidx = m0 >> 10;
  const int s0   = m0 & 1023;   // within-batch token offset (r4 bug: used m0)

#pragma unroll 1
  for (int pl = 0; pl < 2; ++pl) {
    __syncthreads();
#pragma unroll
    for (int i = 0; i < 4; ++i)
#pragma unroll
      for (int j = 0; j < 4; ++j) {
        int n  = wn + j * 16 + lm;
        int mb = wm + i * 16 + g * 4;
        int chunk = mb >> 3;
        int cs = chunk ^ (n & 7);
        *(uint2*)&smem[n * 128 + cs * 8 + (g & 1) * 4] =
            pl ? lpk[i][j] : hpk[i][j];
      }
    __syncthreads();
    {
      int nl = t >> 1, hf = t & 1;
      int colf = n0 + nl;
      int hh = colf >> 6, d = colf & 63;
      unsigned short* dst = pl ? vtl : vth;
      size_t rb = ((size_t)(bidx * 12 + hh) * 64 + d) * 1024 + s0;
#pragma unroll
      for (int cc = 0; cc < 8; ++cc) {
        int c = hf * 8 + cc;
        int cs = c ^ (nl & 7);
        short8 vv = *(const short8*)&smem[nl * 128 + cs * 8];
        *(short8*)&dst[rb + c * 8] = vv;
      }
    }
  }
}

// ---------------------------------------------------------------------------
// MFMA flash attention, swapped operands: QK^T = mfma(K,Q) -> D[key][q],
// PV = mfma(VT,P) -> D[d][q]. Softmax per-lane (q = lm), 2 shfl per reduce.
// P round-trips via per-wave LDS (stride-72 rows), hi then lo planes.
// LDS = 32KB (K/VT) + 18KB (P) = 50KB.
// ---------------------------------------------------------------------------
__global__ __launch_bounds__(256) void attn_mfma_kernel(
    const unsigned short* __restrict__ qhp, const unsigned short* __restrict__ qlp,
    const unsigned short* __restrict__ khp, const unsigned short* __restrict__ klp,
    const unsigned short* __restrict__ vth, const unsigned short* __restrict__ vtl,
    unsigned short* __restrict__ oh, unsigned short* __restrict__ ol) {
  __shared__ __align__(16) short sK0[4096], sK1[4096], sVT0[4096], sVT1[4096];
  __shared__ __align__(16) short sP[4][2304];
  const int t  = threadIdx.x;
  const int wv = t >> 6, l = t & 63, lm = l & 15, g = l >> 4;
  const int bh  = blockIdx.x >> 3;
  const int qw0 = (blockIdx.x & 7) * 128 + wv * 32;

  // Q fragments (layout identical whether used as A- or B-operand)
  short8 qfh[2][2], qfl[2][2];
#pragma unroll
  for (int i = 0; i < 2; ++i) {
    size_t base = ((size_t)bh * 1024 + qw0 + i * 16 + lm) * 64;
#pragma unroll
    for (int tt = 0; tt < 2; ++tt) {
      qfh[i][tt] = *(const short8*)&qhp[base + tt * 32 + g * 8];
      qfl[i][tt] = *(const short8*)&qlp[base + tt * 32 + g * 8];
    }
  }

  float mrun[2] = {-1e30f, -1e30f}, lrun[2] = {0.f, 0.f};
  floatx4 o[2][4];
#pragma unroll
  for (int i = 0; i < 2; ++i)
#pragma unroll
    for (int jd = 0; jd < 4; ++jd) o[i][jd] = (floatx4){0.f, 0.f, 0.f, 0.f};

  short* stage_arr = (wv == 0) ? sK0 : (wv == 1) ? sK1 : (wv == 2) ? sVT0 : sVT1;
  const unsigned short* stage_src =
      (wv == 0) ? khp : (wv == 1) ? klp : (wv == 2) ? vth : vtl;
  const int isV = (wv >= 2);
  short* sPw = sP[wv];

#pragma unroll 1
  for (int kt = 0; kt < 16; ++kt) {
    __syncthreads();
#pragma unroll
    for (int qi = 0; qi < 8; ++qi) {
      int c = qi * 64 + l;
      int row = c >> 3, s = c & 7;
      int gs = s ^ (row & 7);
      const unsigned short* gp = isV
          ? stage_src + ((size_t)bh * 64 + row) * 1024 + kt * 64 + gs * 8
          : stage_src + ((size_t)bh * 1024 + kt * 64 + row) * 64 + gs * 8;
      __builtin_amdgcn_global_load_lds((as1_cu32*)(const void*)gp,
                                       (as3_u32*)(void*)(stage_arr + qi * 512),
                                       16, 0, 0);
    }
    __syncthreads();

    // ---- QK^T swapped: sacc[i][j] = D[key g*4+r (block j)][q lm (block i)]
    floatx4 sacc[2][4];
#pragma unroll
    for (int i = 0; i < 2; ++i)
#pragma unroll
      for (int j = 0; j < 4; ++j) sacc[i][j] = (floatx4){0.f, 0.f, 0.f, 0.f};
#pragma unroll
    for (int tt = 0; tt < 2; ++tt) {
#pragma unroll
      for (int j = 0; j < 4; ++j) {
        int row = j * 16 + lm;
        int so = ((4 * tt + g) ^ (row & 7)) * 8;
        short8 kfh = *(const short8*)&sK0[row * 64 + so];
        short8 kfl = *(const short8*)&sK1[row * 64 + so];
#pragma unroll
        for (int i = 0; i < 2; ++i) {
          sacc[i][j] = __builtin_amdgcn_mfma_f32_16x16x32_bf16(kfh, qfh[i][tt], sacc[i][j], 0, 0, 0);
          sacc[i][j] = __builtin_amdgcn_mfma_f32_16x16x32_bf16(kfh, qfl[i][tt], sacc[i][j], 0, 0, 0);
          sacc[i][j] = __builtin_amdgcn_mfma_f32_16x16x32_bf16(kfl, qfh[i][tt], sacc[i][j], 0, 0, 0);
        }
      }
    }

    // ---- per-lane online softmax (q-row = qw0 + i*16 + lm) ----
    float p[2][16];
    uint2 lpk[2][4];
#pragma unroll
    for (int i = 0; i < 2; ++i) {
      float mt = -1e30f;
#pragma unroll
      for (int j = 0; j < 4; ++j)
#pragma unroll
        for (int r = 0; r < 4; ++r) mt = fmaxf(mt, sacc[i][j][r]);
      mt = fmaxf(mt, __shfl_xor(mt, 16));
      mt = fmaxf(mt, __shfl_xor(mt, 32));
      float mn = fmaxf(mrun[i], mt);
      float corr = __expf(mrun[i] - mn);
      mrun[i] = mn;
      float ps = 0.f;
#pragma unroll
      for (int j = 0; j < 4; ++j)
#pragma unroll
        for (int r = 0; r < 4; ++r) {
          float e = __expf(sacc[i][j][r] - mn);
          p[i][j * 4 + r] = e; ps += e;
        }
      ps += __shfl_xor(ps, 16);
      ps += __shfl_xor(ps, 32);
      lrun[i] = lrun[i] * corr + ps;
#pragma unroll
      for (int jd = 0; jd < 4; ++jd)
#pragma unroll
        for (int r = 0; r < 4; ++r) o[i][jd][r] *= corr;
    }

    // ---- write Ph to per-wave LDS; keep Pl packed in regs ----
#pragma unroll
    for (int i = 0; i < 2; ++i)
#pragma unroll
      for (int j = 0; j < 4; ++j) {
        unsigned short hv[4], lv[4];
#pragma unroll
        for (int r = 0; r < 4; ++r) bsplit(p[i][j * 4 + r], hv[r], lv[r]);
        *(uint2*)&sPw[(i * 16 + lm) * 72 + j * 16 + g * 4] =
            make_uint2((unsigned)hv[0] | ((unsigned)hv[1] << 16),
                       (unsigned)hv[2] | ((unsigned)hv[3] << 16));
        lpk[i][j] = make_uint2((unsigned)lv[0] | ((unsigned)lv[1] << 16),
                               (unsigned)lv[2] | ((unsigned)lv[3] << 16));
      }
    short8 pf[2][2];
#pragma unroll
    for (int i = 0; i < 2; ++i)
#pragma unroll
      for (int tt = 0; tt < 2; ++tt)
        pf[i][tt] = *(const short8*)&sPw[(i * 16 + lm) * 72 + tt * 32 + g * 8];

    // ---- PV terms Vh*Ph + Vl*Ph ----
#pragma unroll
    for (int tt = 0; tt < 2; ++tt) {
#pragma unroll
      for (int jd = 0; jd < 4; ++jd) {
        int row = jd * 16 + lm;
        int so = ((4 * tt + g) ^ (row & 7)) * 8;
        short8 vfh = *(const short8*)&sVT0[row * 64 + so];
        short8 vfl = *(const short8*)&sVT1[row * 64 + so];
#pragma unroll
        for (int i = 0; i < 2; ++i) {
          o[i][jd] = __builtin_amdgcn_mfma_f32_16x16x32_bf16(vfh, pf[i][tt], o[i][jd], 0, 0, 0);
          o[i][jd] = __builtin_amdgcn_mfma_f32_16x16x32_bf16(vfl, pf[i][tt], o[i][jd], 0, 0, 0);
        }
      }
    }

    // ---- write Pl (reuse buffer), term Vh*Pl ----
#pragma unroll
    for (int i = 0; i < 2; ++i)
#pragma unroll
      for (int j = 0; j < 4; ++j)
        *(uint2*)&sPw[(i * 16 + lm) * 72 + j * 16 + g * 4] = lpk[i][j];
#pragma unroll
    for (int i = 0; i < 2; ++i)
#pragma unroll
      for (int tt = 0; tt < 2; ++tt)
        pf[i][tt] = *(const short8*)&sPw[(i * 16 + lm) * 72 + tt * 32 + g * 8];
#pragma unroll
    for (int tt = 0; tt < 2; ++tt) {
#pragma unroll
      for (int jd = 0; jd < 4; ++jd) {
        int row = jd * 16 + lm;
        int so = ((4 * tt + g) ^ (row & 7)) * 8;
        short8 vfh = *(const short8*)&sVT0[row * 64 + so];
#pragma unroll
        for (int i = 0; i < 2; ++i)
          o[i][jd] = __builtin_amdgcn_mfma_f32_16x16x32_bf16(vfh, pf[i][tt], o[i][jd], 0, 0, 0);
      }
    }
  }

  // ---- epilogue: lane owns q-row, d-runs of 4 -> packed 8B stores ----
  const int b = bh / 12, h = bh % 12;
#pragma unroll
  for (int i = 0; i < 2; ++i) {
    float inv = 1.f / lrun[i];
    int q = qw0 + i * 16 + lm;
#pragma unroll
    for (int jd = 0; jd < 4; ++jd) {
      unsigned short hv[4], lv[4];
#pragma unroll
      for (int r = 0; r < 4; ++r) bsplit(o[i][jd][r] * inv, hv[r], lv[r]);
      size_t off = ((size_t)(b * 1024) + q) * 768 + h * 64 + jd * 16 + g * 4;
      *(uint2*)&oh[off] = make_uint2((unsigned)hv[0] | ((unsigned)hv[1] << 16),
                                     (unsigned)hv[2] | ((unsigned)hv[3] << 16));
      *(uint2*)&ol[off] = make_uint2((unsigned)lv[0] | ((unsigned)lv[1] << 16),
                                     (unsigned)lv[2] | ((unsigned)lv[3] << 16));
    }
  }
}

// ---------------------------------------------------------------------------
// Output projection (MFMA) — verified round 2.
// ---------------------------------------------------------------------------
__global__ __launch_bounds__(256) void proj_mfma_kernel(
    const unsigned short* __restrict__ ah_, const unsigned short* __restrict__ al_,
    const unsigned short* __restrict__ wh_, const unsigned short* __restrict__ wl_,
    const float* __restrict__ bo, float* __restrict__ out) {
  __shared__ __align__(16) short sAh[4096], sAl[4096], sBh[4096], sBl[4096];
  const int t  = threadIdx.x;
  const int m0 = blockIdx.x * 128;
  const int n0 = blockIdx.y * 128;

  GEMM_MAIN_LOOP(ah_, al_, wh_, wl_, m0, n0)

#pragma unroll
  for (int j = 0; j < 4; ++j) {
    int n = n0 + wn + j * 16 + lm;
    float bsv = bo[n];
#pragma unroll
    for (int i = 0; i < 4; ++i) {
#pragma unroll
      for (int r = 0; r < 4; ++r) {
        int m = m0 + wm + i * 16 + g * 4 + r;
        out[(size_t)m * 768 + n] = acc[i][j][r] + bsv;
      }
    }
  }
}

// ---------------------------------------------------------------------------
extern "C" void kernel_launch(void* const* d_in, const int* in_sizes, int n_in,
                              void* d_out, int out_size, void* d_ws, size_t ws_size,
                              hipStream_t stream) {
  const float* x  = (const float*)d_in[0];
  const float* Wq = (const float*)d_in[1];
  const float* bq = (const float*)d_in[2];
  const float* Wk = (const float*)d_in[3];
  const float* bk = (const float*)d_in[4];
  const float* Wv = (const float*)d_in[5];
  const float* bv = (const float*)d_in[6];
  const float* Wo = (const float*)d_in[7];
  const float* bo = (const float*)d_in[8];
  float* out = (float*)d_out;

  char* w = (char*)d_ws;
  float* tab          = (float*)(w);                      // 262144
  unsigned short* wth = (unsigned short*)(w + 262144);    // 3538944
  unsigned short* wtl = (unsigned short*)(w + 3801088);   // 3538944
  unsigned short* woh = (unsigned short*)(w + 7340032);   // 1179648
  unsigned short* wol = (unsigned short*)(w + 8519680);   // 1179648
  unsigned short* xh  = (unsigned short*)(w + 9699328);   // 12582912 (reused: attn out hi)
  unsigned short* xl  = (unsigned short*)(w + 22282240);  // 12582912 (reused: attn out lo)
  unsigned short* qh  = (unsigned short*)(w + 34865152);  // 12582912
  unsigned short* ql  = (unsigned short*)(w + 47448064);
  unsigned short* kh  = (unsigned short*)(w + 60030976);
  unsigned short* kl  = (unsigned short*)(w + 72613888);
  unsigned short* vth = (unsigned short*)(w + 85196800);
  unsigned short* vtl = (unsigned short*)(w + 97779712);  // end 110362624

  rope_tab_kernel<<<dim3(128), dim3(256), 0, stream>>>(tab);
  xconv_kernel<<<dim3(6144), dim3(256), 0, stream>>>(x, xh, xl);
  wconv_kernel<<<dim3(24, 24, 4), dim3(256), 0, stream>>>(
      Wq, Wk, Wv, Wo, wth, wtl, woh, wol);
  qk_mfma_kernel<<<dim3(64, 12), dim3(256), 0, stream>>>(
      xh, xl, wth, wtl, bq, bk, tab, qh, ql, kh, kl);
  v_mfma_kernel<<<dim3(64, 6), dim3(256), 0, stream>>>(
      xh, xl, wth + (size_t)2 * 768 * 768, wtl + (size_t)2 * 768 * 768,
      bv, vth, vtl);
  attn_mfma_kernel<<<dim3(768), dim3(256), 0, stream>>>(
      qh, ql, kh, kl, vth, vtl, xh, xl);
  proj_mfma_kernel<<<dim3(64, 6), dim3(256), 0, stream>>>(
      xh, xl, woh, wol, bo, out);
}

// Round 6
// 319.132 us; speedup vs baseline: 3.6323x; 1.2196x over previous
//
#include <hip/hip_runtime.h>
#include <hip/hip_bf16.h>
#include <math.h>

typedef __attribute__((ext_vector_type(8))) short short8;
typedef __attribute__((ext_vector_type(8))) _Float16 half8;
typedef __attribute__((ext_vector_type(4))) float floatx4;
typedef const unsigned int __attribute__((address_space(1))) as1_cu32;
typedef unsigned int __attribute__((address_space(3))) as3_u32;

// ---------------- fp16 split helpers ----------------
__device__ __forceinline__ unsigned short h16(float x) {
  union { _Float16 f; unsigned short u; } c; c.f = (_Float16)x; return c.u;
}
__device__ __forceinline__ float h2f(unsigned short u) {
  union { _Float16 f; unsigned short u; } c; c.u = u; return (float)c.f;
}
__device__ __forceinline__ void hsplit(float x, unsigned short& h, unsigned short& l) {
  h = h16(x); l = h16(x - h2f(h));
}

// ---------------------------------------------------------------------------
// RoPE table
// ---------------------------------------------------------------------------
__global__ void rope_tab_kernel(float* __restrict__ tab) {
  int idx = blockIdx.x * 256 + threadIdx.x;
  if (idx >= 32768) return;
  int s  = idx >> 5, k2 = idx & 31;
  int r  = s >> 5,  c  = s & 31;
  int j  = k2 & 15;
  float f   = expf(-(float)j * (9.210340371976184f / 16.0f));
  float pos = (k2 < 16) ? (float)r : (float)c;
  float a   = pos * f;
  tab[2*idx]   = cosf(a);
  tab[2*idx+1] = sinf(a);
}

// ---------------------------------------------------------------------------
// x -> hi/lo fp16
// ---------------------------------------------------------------------------
__global__ __launch_bounds__(256) void xconv_kernel(
    const float* __restrict__ x, unsigned short* __restrict__ xh,
    unsigned short* __restrict__ xl) {
  int i = (blockIdx.x * 256 + threadIdx.x) * 4;
  float4 f = *(const float4*)&x[i];
  ushort4 h, l;
  hsplit(f.x, h.x, l.x); hsplit(f.y, h.y, l.y);
  hsplit(f.z, h.z, l.z); hsplit(f.w, h.w, l.w);
  *(ushort4*)&xh[i] = h;
  *(ushort4*)&xl[i] = l;
}

// ---------------------------------------------------------------------------
// W -> Wt single fp16 [N][K].  z=0,1,2 -> Wq,Wk,Wv into wt; z=3 -> Wo.
// ---------------------------------------------------------------------------
__global__ __launch_bounds__(256) void wconv_kernel(
    const float* __restrict__ Wq, const float* __restrict__ Wk,
    const float* __restrict__ Wv, const float* __restrict__ Wo,
    unsigned short* __restrict__ wt, unsigned short* __restrict__ wo) {
  __shared__ float tile[32][33];
  int z = blockIdx.z;
  const float* src = (z == 0) ? Wq : (z == 1) ? Wk : (z == 2) ? Wv : Wo;
  unsigned short* dh = (z < 3) ? wt + (size_t)z * 589824 : wo;
  int k0 = blockIdx.x * 32, n0 = blockIdx.y * 32;
  int tx = threadIdx.x & 31, ty = threadIdx.x >> 5;
#pragma unroll
  for (int r = 0; r < 4; ++r)
    tile[ty + r * 8][tx] = src[(size_t)(k0 + ty + r * 8) * 768 + n0 + tx];
  __syncthreads();
#pragma unroll
  for (int r = 0; r < 4; ++r) {
    int n = n0 + ty + r * 8;
    dh[(size_t)n * 768 + k0 + tx] = h16(tile[tx][ty + r * 8]);
  }
}

// ---------------------------------------------------------------------------
// MFMA GEMM core (128x128 tile, BK=32, 4 waves, fp16 2-term: A split, B single)
// ---------------------------------------------------------------------------
__device__ __forceinline__ void stage_tile(const unsigned short* __restrict__ src,
                                           int row0, int k0, short* lds, int t) {
  int l  = t & 63;
  int wb = t & 192;
#pragma unroll
  for (int r = 0; r < 2; ++r) {
    int cbase = r * 256 + wb;
    int c = cbase + l;
    int m = c >> 2, s = c & 3;
    int g = s ^ (m & 3);
    const unsigned short* gp = src + (size_t)(row0 + m) * 768 + k0 + g * 8;
    __builtin_amdgcn_global_load_lds((as1_cu32*)(const void*)gp,
                                     (as3_u32*)(void*)(lds + cbase * 8),
                                     16, 0, 0);
  }
}

#define GEMM_MAIN_LOOP2(Ah, Al, Bs, m0, n0)                                      \
  floatx4 acc[4][4];                                                             \
  _Pragma("unroll") for (int i = 0; i < 4; ++i)                                  \
      _Pragma("unroll") for (int j = 0; j < 4; ++j)                              \
          acc[i][j] = (floatx4){0.f, 0.f, 0.f, 0.f};                             \
  const int l  = t & 63;                                                         \
  const int lm = l & 15, g = l >> 4;                                             \
  const int wm = ((t >> 7) & 1) * 64, wn = ((t >> 6) & 1) * 64;                  \
  const int sl = g ^ (lm & 3);                                                   \
  for (int k0 = 0; k0 < 768; k0 += 32) {                                         \
    __syncthreads();                                                             \
    stage_tile(Ah, m0, k0, sAh, t);                                              \
    stage_tile(Al, m0, k0, sAl, t);                                              \
    stage_tile(Bs, n0, k0, sB, t);                                               \
    __syncthreads();                                                             \
    half8 ah[4], al[4];                                                          \
    _Pragma("unroll") for (int i = 0; i < 4; ++i) {                              \
      int ra = wm + i * 16 + lm;                                                 \
      ah[i] = *(const half8*)&sAh[ra * 32 + sl * 8];                             \
      al[i] = *(const half8*)&sAl[ra * 32 + sl * 8];                             \
    }                                                                            \
    _Pragma("unroll") for (int j = 0; j < 4; ++j) {                              \
      int rb = wn + j * 16 + lm;                                                 \
      half8 b8 = *(const half8*)&sB[rb * 32 + sl * 8];                           \
      _Pragma("unroll") for (int i = 0; i < 4; ++i) {                            \
        acc[i][j] = __builtin_amdgcn_mfma_f32_16x16x32_f16(ah[i], b8, acc[i][j], 0, 0, 0); \
        acc[i][j] = __builtin_amdgcn_mfma_f32_16x16x32_f16(al[i], b8, acc[i][j], 0, 0, 0); \
      }                                                                          \
    }                                                                            \
  }

// ---------------------------------------------------------------------------
// Q/K projection: RoPE epilogue. q -> hi/lo fp16 [B,H,S,64]; k -> single fp16.
// ---------------------------------------------------------------------------
__global__ __launch_bounds__(256) void qk_mfma_kernel(
    const unsigned short* __restrict__ xh, const unsigned short* __restrict__ xl,
    const unsigned short* __restrict__ wt,
    const float* __restrict__ bq, const float* __restrict__ bk,
    const float* __restrict__ tab,
    unsigned short* __restrict__ qhp, unsigned short* __restrict__ qlp,
    unsigned short* __restrict__ khp) {
  __shared__ __align__(16) short sAh[4096], sAl[4096], sB[4096];
  const int t  = threadIdx.x;
  const int m0 = blockIdx.x * 128;
  const int n0 = blockIdx.y * 128;

  GEMM_MAIN_LOOP2(xh, xl, wt, m0, n0)

  const int proj = n0 / 768;
  const int col0 = n0 % 768;
  const float* bias = (proj == 0) ? bq : bk;
  const float qs = (proj == 0) ? 0.125f : 1.f;

#pragma unroll
  for (int j = 0; j < 4; ++j) {
    int colf = col0 + wn + j * 16;
    int hh = colf >> 6;
    int d  = (colf & 63) + lm;
    float bsv = bias[colf + lm];
    int kidx = (d < 32) ? (d >> 1) : (16 + ((d - 32) >> 1));
    float sgn = (d & 1) ? 1.f : -1.f;
#pragma unroll
    for (int i = 0; i < 4; ++i) {
#pragma unroll
      for (int r = 0; r < 4; ++r) {
        int m = m0 + wm + i * 16 + g * 4 + r;
        int b = m >> 10, sidx = m & 1023;
        float val = acc[i][j][r] + bsv;
        float2 cssn = *(const float2*)&tab[(sidx * 32 + kidx) * 2];
        float p = __shfl_xor(val, 1);
        val = (val * cssn.x + sgn * (p * cssn.y)) * qs;
        size_t off = (((size_t)(b * 12 + hh)) * 1024 + sidx) * 64 + (d & ~1);
        if (proj == 0) {
          unsigned short hv, lv; hsplit(val, hv, lv);
          unsigned hx = (unsigned)__shfl_xor((int)hv, 1);
          unsigned lx = (unsigned)__shfl_xor((int)lv, 1);
          if ((lm & 1) == 0)
            *(unsigned*)&qhp[off] = ((hx & 0xffffu) << 16) | (unsigned)hv;
          else
            *(unsigned*)&qlp[off] = (((unsigned)lv) << 16) | (lx & 0xffffu);
        } else {
          unsigned short hv = h16(val);
          unsigned hx = (unsigned)__shfl_xor((int)hv, 1);
          if ((lm & 1) == 0)
            *(unsigned*)&khp[off] = ((hx & 0xffffu) << 16) | (unsigned)hv;
        }
      }
    }
  }
}

// ---------------------------------------------------------------------------
// V projection with LDS-transposed coalesced single-fp16 V^T [B,H,64,S].
// ---------------------------------------------------------------------------
__global__ __launch_bounds__(256) void v_mfma_kernel(
    const unsigned short* __restrict__ xh, const unsigned short* __restrict__ xl,
    const unsigned short* __restrict__ wv_, const float* __restrict__ bv,
    unsigned short* __restrict__ vtp) {
  __shared__ __align__(16) short smem[16384];
  short* sAh = smem;         short* sAl = smem + 4096;
  short* sB  = smem + 8192;
  const int t  = threadIdx.x;
  const int m0 = blockIdx.x * 128;
  const int n0 = blockIdx.y * 128;

  GEMM_MAIN_LOOP2(xh, xl, wv_, m0, n0)

  uint2 hpk[4][4];
#pragma unroll
  for (int j = 0; j < 4; ++j) {
    float bsv = bv[n0 + wn + j * 16 + lm];
#pragma unroll
    for (int i = 0; i < 4; ++i) {
      unsigned short hv[4];
#pragma unroll
      for (int r = 0; r < 4; ++r) hv[r] = h16(acc[i][j][r] + bsv);
      hpk[i][j] = make_uint2((unsigned)hv[0] | ((unsigned)hv[1] << 16),
                             (unsigned)hv[2] | ((unsigned)hv[3] << 16));
    }
  }
  const int bidx = m0 >> 10;
  const int s0   = m0 & 1023;

  __syncthreads();
#pragma unroll
  for (int i = 0; i < 4; ++i)
#pragma unroll
    for (int j = 0; j < 4; ++j) {
      int n  = wn + j * 16 + lm;
      int mb = wm + i * 16 + g * 4;
      int chunk = mb >> 3;
      int cs = chunk ^ (n & 7);
      *(uint2*)&smem[n * 128 + cs * 8 + (g & 1) * 4] = hpk[i][j];
    }
  __syncthreads();
  {
    int nl = t >> 1, hf = t & 1;
    int colf = n0 + nl;
    int hh = colf >> 6, d = colf & 63;
    size_t rb = ((size_t)(bidx * 12 + hh) * 64 + d) * 1024 + s0;
#pragma unroll
    for (int cc = 0; cc < 8; ++cc) {
      int c = hf * 8 + cc;
      int cs = c ^ (nl & 7);
      *(short8*)&vtp[rb + c * 8] = *(const short8*)&smem[nl * 128 + cs * 8];
    }
  }
}

// ---------------------------------------------------------------------------
// MFMA flash attention (fp16): QK^T = mfma(K, Qh)+mfma(K, Ql) -> D[key][q];
// PV = mfma(VT, P) single-term. Per-lane softmax (q = lm), 2 shfl/reduce.
// K,V,P single fp16; Q split. LDS = 8+8+18 = 34 KB.
// ---------------------------------------------------------------------------
__global__ __launch_bounds__(256) void attn_mfma_kernel(
    const unsigned short* __restrict__ qhp, const unsigned short* __restrict__ qlp,
    const unsigned short* __restrict__ khp, const unsigned short* __restrict__ vtp,
    unsigned short* __restrict__ oh, unsigned short* __restrict__ ol) {
  __shared__ __align__(16) short sK[4096], sVT[4096];
  __shared__ __align__(16) short sP[4][2304];
  const int t  = threadIdx.x;
  const int wv = t >> 6, l = t & 63, lm = l & 15, g = l >> 4;
  const int bh  = blockIdx.x >> 3;
  const int qw0 = (blockIdx.x & 7) * 128 + wv * 32;

  half8 qfh[2][2], qfl[2][2];
#pragma unroll
  for (int i = 0; i < 2; ++i) {
    size_t base = ((size_t)bh * 1024 + qw0 + i * 16 + lm) * 64;
#pragma unroll
    for (int tt = 0; tt < 2; ++tt) {
      qfh[i][tt] = *(const half8*)&qhp[base + tt * 32 + g * 8];
      qfl[i][tt] = *(const half8*)&qlp[base + tt * 32 + g * 8];
    }
  }

  float mrun[2] = {-1e30f, -1e30f}, lrun[2] = {0.f, 0.f};
  floatx4 o[2][4];
#pragma unroll
  for (int i = 0; i < 2; ++i)
#pragma unroll
    for (int jd = 0; jd < 4; ++jd) o[i][jd] = (floatx4){0.f, 0.f, 0.f, 0.f};

  short* sPw = sP[wv];

#pragma unroll 1
  for (int kt = 0; kt < 16; ++kt) {
    __syncthreads();
    // stage K (chunks 0..511) and VT (512..1023); per-wave-uniform LDS bases
#pragma unroll
    for (int qi = 0; qi < 4; ++qi) {
      int cz = qi * 256 + t;
      int plane = cz >> 9;
      int c = cz & 511;
      int row = c >> 3, s = c & 7;
      int gs = s ^ (row & 7);
      const unsigned short* gp = plane
          ? vtp + ((size_t)bh * 64 + row) * 1024 + kt * 64 + gs * 8
          : khp + ((size_t)bh * 1024 + kt * 64 + row) * 64 + gs * 8;
      short* dst = (plane ? sVT : sK) + c * 8;
      __builtin_amdgcn_global_load_lds((as1_cu32*)(const void*)gp,
                                       (as3_u32*)(void*)dst, 16, 0, 0);
    }
    __syncthreads();

    // ---- QK^T (2 terms, Q exact) ----
    floatx4 sacc[2][4];
#pragma unroll
    for (int i = 0; i < 2; ++i)
#pragma unroll
      for (int j = 0; j < 4; ++j) sacc[i][j] = (floatx4){0.f, 0.f, 0.f, 0.f};
#pragma unroll
    for (int tt = 0; tt < 2; ++tt) {
#pragma unroll
      for (int j = 0; j < 4; ++j) {
        int row = j * 16 + lm;
        int so = ((4 * tt + g) ^ (row & 7)) * 8;
        half8 kf = *(const half8*)&sK[row * 64 + so];
#pragma unroll
        for (int i = 0; i < 2; ++i) {
          sacc[i][j] = __builtin_amdgcn_mfma_f32_16x16x32_f16(kf, qfh[i][tt], sacc[i][j], 0, 0, 0);
          sacc[i][j] = __builtin_amdgcn_mfma_f32_16x16x32_f16(kf, qfl[i][tt], sacc[i][j], 0, 0, 0);
        }
      }
    }

    // ---- per-lane online softmax (q-row = qw0 + i*16 + lm) ----
    float p[2][16];
#pragma unroll
    for (int i = 0; i < 2; ++i) {
      float mt = -1e30f;
#pragma unroll
      for (int j = 0; j < 4; ++j)
#pragma unroll
        for (int r = 0; r < 4; ++r) mt = fmaxf(mt, sacc[i][j][r]);
      mt = fmaxf(mt, __shfl_xor(mt, 16));
      mt = fmaxf(mt, __shfl_xor(mt, 32));
      float mn = fmaxf(mrun[i], mt);
      float corr = __expf(mrun[i] - mn);
      mrun[i] = mn;
      float ps = 0.f;
#pragma unroll
      for (int j = 0; j < 4; ++j)
#pragma unroll
        for (int r = 0; r < 4; ++r) {
          float e = __expf(sacc[i][j][r] - mn);
          p[i][j * 4 + r] = e; ps += e;
        }
      ps += __shfl_xor(ps, 16);
      ps += __shfl_xor(ps, 32);
      lrun[i] = lrun[i] * corr + ps;
#pragma unroll
      for (int jd = 0; jd < 4; ++jd)
#pragma unroll
        for (int r = 0; r < 4; ++r) o[i][jd][r] *= corr;
    }

    // ---- P -> per-wave LDS (single fp16 plane) ----
#pragma unroll
    for (int i = 0; i < 2; ++i)
#pragma unroll
      for (int j = 0; j < 4; ++j) {
        unsigned short hv[4];
#pragma unroll
        for (int r = 0; r < 4; ++r) hv[r] = h16(p[i][j * 4 + r]);
        *(uint2*)&sPw[(i * 16 + lm) * 72 + j * 16 + g * 4] =
            make_uint2((unsigned)hv[0] | ((unsigned)hv[1] << 16),
                       (unsigned)hv[2] | ((unsigned)hv[3] << 16));
      }
    half8 pf[2][2];
#pragma unroll
    for (int i = 0; i < 2; ++i)
#pragma unroll
      for (int tt = 0; tt < 2; ++tt)
        pf[i][tt] = *(const half8*)&sPw[(i * 16 + lm) * 72 + tt * 32 + g * 8];

    // ---- PV (single term) ----
#pragma unroll
    for (int tt = 0; tt < 2; ++tt) {
#pragma unroll
      for (int jd = 0; jd < 4; ++jd) {
        int row = jd * 16 + lm;
        int so = ((4 * tt + g) ^ (row & 7)) * 8;
        half8 vf = *(const half8*)&sVT[row * 64 + so];
#pragma unroll
        for (int i = 0; i < 2; ++i)
          o[i][jd] = __builtin_amdgcn_mfma_f32_16x16x32_f16(vf, pf[i][tt], o[i][jd], 0, 0, 0);
      }
    }
  }

  // ---- epilogue: normalize, hi/lo fp16 out [B,S,768] ----
  const int b = bh / 12, h = bh % 12;
#pragma unroll
  for (int i = 0; i < 2; ++i) {
    float inv = 1.f / lrun[i];
    int q = qw0 + i * 16 + lm;
#pragma unroll
    for (int jd = 0; jd < 4; ++jd) {
      unsigned short hv[4], lv[4];
#pragma unroll
      for (int r = 0; r < 4; ++r) hsplit(o[i][jd][r] * inv, hv[r], lv[r]);
      size_t off = ((size_t)(b * 1024) + q) * 768 + h * 64 + jd * 16 + g * 4;
      *(uint2*)&oh[off] = make_uint2((unsigned)hv[0] | ((unsigned)hv[1] << 16),
                                     (unsigned)hv[2] | ((unsigned)hv[3] << 16));
      *(uint2*)&ol[off] = make_uint2((unsigned)lv[0] | ((unsigned)lv[1] << 16),
                                     (unsigned)lv[2] | ((unsigned)lv[3] << 16));
    }
  }
}

// ---------------------------------------------------------------------------
// Output projection (2-term fp16): out = A @ Wo + bo, fp32 out.
// ---------------------------------------------------------------------------
__global__ __launch_bounds__(256) void proj_mfma_kernel(
    const unsigned short* __restrict__ ah_, const unsigned short* __restrict__ al_,
    const unsigned short* __restrict__ wo_, const float* __restrict__ bo,
    float* __restrict__ out) {
  __shared__ __align__(16) short sAh[4096], sAl[4096], sB[4096];
  const int t  = threadIdx.x;
  const int m0 = blockIdx.x * 128;
  const int n0 = blockIdx.y * 128;

  GEMM_MAIN_LOOP2(ah_, al_, wo_, m0, n0)

#pragma unroll
  for (int j = 0; j < 4; ++j) {
    int n = n0 + wn + j * 16 + lm;
    float bsv = bo[n];
#pragma unroll
    for (int i = 0; i < 4; ++i) {
#pragma unroll
      for (int r = 0; r < 4; ++r) {
        int m = m0 + wm + i * 16 + g * 4 + r;
        out[(size_t)m * 768 + n] = acc[i][j][r] + bsv;
      }
    }
  }
}

// ---------------------------------------------------------------------------
extern "C" void kernel_launch(void* const* d_in, const int* in_sizes, int n_in,
                              void* d_out, int out_size, void* d_ws, size_t ws_size,
                              hipStream_t stream) {
  const float* x  = (const float*)d_in[0];
  const float* Wq = (const float*)d_in[1];
  const float* bq = (const float*)d_in[2];
  const float* Wk = (const float*)d_in[3];
  const float* bk = (const float*)d_in[4];
  const float* Wv = (const float*)d_in[5];
  const float* bv = (const float*)d_in[6];
  const float* Wo = (const float*)d_in[7];
  const float* bo = (const float*)d_in[8];
  float* out = (float*)d_out;

  char* w = (char*)d_ws;
  float* tab          = (float*)(w);                      // 262144
  unsigned short* wt  = (unsigned short*)(w + 262144);    // 3538944 (Wq|Wk|Wv ^T fp16)
  unsigned short* wo  = (unsigned short*)(w + 3801088);   // 1179648
  unsigned short* xh  = (unsigned short*)(w + 4980736);   // 12582912 (reused: attn out hi)
  unsigned short* xl  = (unsigned short*)(w + 17563648);  // 12582912 (reused: attn out lo)
  unsigned short* qh  = (unsigned short*)(w + 30146560);  // 12582912
  unsigned short* ql  = (unsigned short*)(w + 42729472);  // 12582912
  unsigned short* kh  = (unsigned short*)(w + 55312384);  // 12582912
  unsigned short* vt  = (unsigned short*)(w + 67895296);  // 12582912 -> end 80478208

  rope_tab_kernel<<<dim3(128), dim3(256), 0, stream>>>(tab);
  xconv_kernel<<<dim3(6144), dim3(256), 0, stream>>>(x, xh, xl);
  wconv_kernel<<<dim3(24, 24, 4), dim3(256), 0, stream>>>(
      Wq, Wk, Wv, Wo, wt, wo);
  qk_mfma_kernel<<<dim3(64, 12), dim3(256), 0, stream>>>(
      xh, xl, wt, bq, bk, tab, qh, ql, kh);
  v_mfma_kernel<<<dim3(64, 6), dim3(256), 0, stream>>>(
      xh, xl, wt + (size_t)2 * 589824, bv, vt);
  attn_mfma_kernel<<<dim3(768), dim3(256), 0, stream>>>(
      qh, ql, kh, vt, xh, xl);
  proj_mfma_kernel<<<dim3(64, 6), dim3(256), 0, stream>>>(
      xh, xl, wo, bo, out);
}

// Round 7
// 271.896 us; speedup vs baseline: 4.2634x; 1.1737x over previous
//
#include <hip/hip_runtime.h>
#include <hip/hip_bf16.h>
#include <math.h>

typedef __attribute__((ext_vector_type(8))) short short8;
typedef __attribute__((ext_vector_type(8))) _Float16 half8;
typedef __attribute__((ext_vector_type(4))) float floatx4;
typedef const unsigned int __attribute__((address_space(1))) as1_cu32;
typedef unsigned int __attribute__((address_space(3))) as3_u32;

// ---------------- fp16 split helpers ----------------
__device__ __forceinline__ unsigned short h16(float x) {
  union { _Float16 f; unsigned short u; } c; c.f = (_Float16)x; return c.u;
}
__device__ __forceinline__ float h2f(unsigned short u) {
  union { _Float16 f; unsigned short u; } c; c.u = u; return (float)c.f;
}
__device__ __forceinline__ void hsplit(float x, unsigned short& h, unsigned short& l) {
  h = h16(x); l = h16(x - h2f(h));
}

// ---------------------------------------------------------------------------
// RoPE table
// ---------------------------------------------------------------------------
__global__ void rope_tab_kernel(float* __restrict__ tab) {
  int idx = blockIdx.x * 256 + threadIdx.x;
  if (idx >= 32768) return;
  int s  = idx >> 5, k2 = idx & 31;
  int r  = s >> 5,  c  = s & 31;
  int j  = k2 & 15;
  float f   = expf(-(float)j * (9.210340371976184f / 16.0f));
  float pos = (k2 < 16) ? (float)r : (float)c;
  float a   = pos * f;
  tab[2*idx]   = cosf(a);
  tab[2*idx+1] = sinf(a);
}

// ---------------------------------------------------------------------------
// x -> hi/lo fp16
// ---------------------------------------------------------------------------
__global__ __launch_bounds__(256) void xconv_kernel(
    const float* __restrict__ x, unsigned short* __restrict__ xh,
    unsigned short* __restrict__ xl) {
  int i = (blockIdx.x * 256 + threadIdx.x) * 4;
  float4 f = *(const float4*)&x[i];
  ushort4 h, l;
  hsplit(f.x, h.x, l.x); hsplit(f.y, h.y, l.y);
  hsplit(f.z, h.z, l.z); hsplit(f.w, h.w, l.w);
  *(ushort4*)&xh[i] = h;
  *(ushort4*)&xl[i] = l;
}

// ---------------------------------------------------------------------------
// W -> Wt single fp16 [N][K].  z=0,1,2 -> Wq,Wk,Wv into wt; z=3 -> Wo.
// ---------------------------------------------------------------------------
__global__ __launch_bounds__(256) void wconv_kernel(
    const float* __restrict__ Wq, const float* __restrict__ Wk,
    const float* __restrict__ Wv, const float* __restrict__ Wo,
    unsigned short* __restrict__ wt, unsigned short* __restrict__ wo) {
  __shared__ float tile[32][33];
  int z = blockIdx.z;
  const float* src = (z == 0) ? Wq : (z == 1) ? Wk : (z == 2) ? Wv : Wo;
  unsigned short* dh = (z < 3) ? wt + (size_t)z * 589824 : wo;
  int k0 = blockIdx.x * 32, n0 = blockIdx.y * 32;
  int tx = threadIdx.x & 31, ty = threadIdx.x >> 5;
#pragma unroll
  for (int r = 0; r < 4; ++r)
    tile[ty + r * 8][tx] = src[(size_t)(k0 + ty + r * 8) * 768 + n0 + tx];
  __syncthreads();
#pragma unroll
  for (int r = 0; r < 4; ++r) {
    int n = n0 + ty + r * 8;
    dh[(size_t)n * 768 + k0 + tx] = h16(tile[tx][ty + r * 8]);
  }
}

// ---------------------------------------------------------------------------
// MFMA GEMM core: 128x128 tile, BK=32, 4 waves, fp16 2-term, DOUBLE-BUFFERED
// staging (prologue-stage tile0; per step: barrier -> issue next -> compute).
// One barrier per K-step; next-tile load latency hides under 32 MFMAs.
// ---------------------------------------------------------------------------
__device__ __forceinline__ void stage_tile(const unsigned short* __restrict__ src,
                                           int row0, int k0, short* lds, int t) {
  int l  = t & 63;
  int wb = t & 192;
#pragma unroll
  for (int r = 0; r < 2; ++r) {
    int cbase = r * 256 + wb;
    int c = cbase + l;
    int m = c >> 2, s = c & 3;
    int g = s ^ (m & 3);
    const unsigned short* gp = src + (size_t)(row0 + m) * 768 + k0 + g * 8;
    __builtin_amdgcn_global_load_lds((as1_cu32*)(const void*)gp,
                                     (as3_u32*)(void*)(lds + cbase * 8),
                                     16, 0, 0);
  }
}

#define GEMM_MAIN_LOOP_DB(Ah, Al, Bs, m0, n0)                                    \
  floatx4 acc[4][4];                                                             \
  _Pragma("unroll") for (int i = 0; i < 4; ++i)                                  \
      _Pragma("unroll") for (int j = 0; j < 4; ++j)                              \
          acc[i][j] = (floatx4){0.f, 0.f, 0.f, 0.f};                             \
  const int l  = t & 63;                                                         \
  const int lm = l & 15, g = l >> 4;                                             \
  const int wm = ((t >> 7) & 1) * 64, wn = ((t >> 6) & 1) * 64;                  \
  const int sl = g ^ (lm & 3);                                                   \
  stage_tile(Ah, m0, 0, sAh, t);                                                 \
  stage_tile(Al, m0, 0, sAl, t);                                                 \
  stage_tile(Bs, n0, 0, sB, t);                                                  \
  for (int k0 = 0; k0 < 768; k0 += 32) {                                         \
    __syncthreads();                                                             \
    const int cur = (k0 >> 5) & 1, nxt = cur ^ 1;                                \
    if (k0 + 32 < 768) {                                                         \
      stage_tile(Ah, m0, k0 + 32, sAh + nxt * 4096, t);                          \
      stage_tile(Al, m0, k0 + 32, sAl + nxt * 4096, t);                          \
      stage_tile(Bs, n0, k0 + 32, sB  + nxt * 4096, t);                          \
    }                                                                            \
    const short* cAh = sAh + cur * 4096;                                         \
    const short* cAl = sAl + cur * 4096;                                         \
    const short* cB  = sB  + cur * 4096;                                         \
    half8 ah[4], al[4];                                                          \
    _Pragma("unroll") for (int i = 0; i < 4; ++i) {                              \
      int ra = wm + i * 16 + lm;                                                 \
      ah[i] = *(const half8*)&cAh[ra * 32 + sl * 8];                             \
      al[i] = *(const half8*)&cAl[ra * 32 + sl * 8];                             \
    }                                                                            \
    _Pragma("unroll") for (int j = 0; j < 4; ++j) {                              \
      int rb = wn + j * 16 + lm;                                                 \
      half8 b8 = *(const half8*)&cB[rb * 32 + sl * 8];                           \
      _Pragma("unroll") for (int i = 0; i < 4; ++i) {                            \
        acc[i][j] = __builtin_amdgcn_mfma_f32_16x16x32_f16(ah[i], b8, acc[i][j], 0, 0, 0); \
        acc[i][j] = __builtin_amdgcn_mfma_f32_16x16x32_f16(al[i], b8, acc[i][j], 0, 0, 0); \
      }                                                                          \
    }                                                                            \
  }

// ---------------------------------------------------------------------------
// Q/K projection: RoPE epilogue. q -> hi/lo fp16 [B,H,S,64]; k -> single fp16.
// ---------------------------------------------------------------------------
__global__ __launch_bounds__(256) void qk_mfma_kernel(
    const unsigned short* __restrict__ xh, const unsigned short* __restrict__ xl,
    const unsigned short* __restrict__ wt,
    const float* __restrict__ bq, const float* __restrict__ bk,
    const float* __restrict__ tab,
    unsigned short* __restrict__ qhp, unsigned short* __restrict__ qlp,
    unsigned short* __restrict__ khp) {
  __shared__ __align__(16) short sAh[8192], sAl[8192], sB[8192];
  const int t  = threadIdx.x;
  const int m0 = blockIdx.x * 128;
  const int n0 = blockIdx.y * 128;

  GEMM_MAIN_LOOP_DB(xh, xl, wt, m0, n0)

  const int proj = n0 / 768;
  const int col0 = n0 % 768;
  const float* bias = (proj == 0) ? bq : bk;
  const float qs = (proj == 0) ? 0.125f : 1.f;

#pragma unroll
  for (int j = 0; j < 4; ++j) {
    int colf = col0 + wn + j * 16;
    int hh = colf >> 6;
    int d  = (colf & 63) + lm;
    float bsv = bias[colf + lm];
    int kidx = (d < 32) ? (d >> 1) : (16 + ((d - 32) >> 1));
    float sgn = (d & 1) ? 1.f : -1.f;
#pragma unroll
    for (int i = 0; i < 4; ++i) {
#pragma unroll
      for (int r = 0; r < 4; ++r) {
        int m = m0 + wm + i * 16 + g * 4 + r;
        int b = m >> 10, sidx = m & 1023;
        float val = acc[i][j][r] + bsv;
        float2 cssn = *(const float2*)&tab[(sidx * 32 + kidx) * 2];
        float p = __shfl_xor(val, 1);
        val = (val * cssn.x + sgn * (p * cssn.y)) * qs;
        size_t off = (((size_t)(b * 12 + hh)) * 1024 + sidx) * 64 + (d & ~1);
        if (proj == 0) {
          unsigned short hv, lv; hsplit(val, hv, lv);
          unsigned hx = (unsigned)__shfl_xor((int)hv, 1);
          unsigned lx = (unsigned)__shfl_xor((int)lv, 1);
          if ((lm & 1) == 0)
            *(unsigned*)&qhp[off] = ((hx & 0xffffu) << 16) | (unsigned)hv;
          else
            *(unsigned*)&qlp[off] = (((unsigned)lv) << 16) | (lx & 0xffffu);
        } else {
          unsigned short hv = h16(val);
          unsigned hx = (unsigned)__shfl_xor((int)hv, 1);
          if ((lm & 1) == 0)
            *(unsigned*)&khp[off] = ((hx & 0xffffu) << 16) | (unsigned)hv;
        }
      }
    }
  }
}

// ---------------------------------------------------------------------------
// V projection with LDS-transposed coalesced single-fp16 V^T [B,H,64,S].
// Transpose reuses the first 32KB of the staging LDS after the main loop.
// ---------------------------------------------------------------------------
__global__ __launch_bounds__(256) void v_mfma_kernel(
    const unsigned short* __restrict__ xh, const unsigned short* __restrict__ xl,
    const unsigned short* __restrict__ wv_, const float* __restrict__ bv,
    unsigned short* __restrict__ vtp) {
  __shared__ __align__(16) short smem[24576];
  short* sAh = smem;          short* sAl = smem + 8192;
  short* sB  = smem + 16384;
  const int t  = threadIdx.x;
  const int m0 = blockIdx.x * 128;
  const int n0 = blockIdx.y * 128;

  GEMM_MAIN_LOOP_DB(xh, xl, wv_, m0, n0)

  uint2 hpk[4][4];
#pragma unroll
  for (int j = 0; j < 4; ++j) {
    float bsv = bv[n0 + wn + j * 16 + lm];
#pragma unroll
    for (int i = 0; i < 4; ++i) {
      unsigned short hv[4];
#pragma unroll
      for (int r = 0; r < 4; ++r) hv[r] = h16(acc[i][j][r] + bsv);
      hpk[i][j] = make_uint2((unsigned)hv[0] | ((unsigned)hv[1] << 16),
                             (unsigned)hv[2] | ((unsigned)hv[3] << 16));
    }
  }
  const int bidx = m0 >> 10;
  const int s0   = m0 & 1023;

  __syncthreads();
#pragma unroll
  for (int i = 0; i < 4; ++i)
#pragma unroll
    for (int j = 0; j < 4; ++j) {
      int n  = wn + j * 16 + lm;
      int mb = wm + i * 16 + g * 4;
      int chunk = mb >> 3;
      int cs = chunk ^ (n & 7);
      *(uint2*)&smem[n * 128 + cs * 8 + (g & 1) * 4] = hpk[i][j];
    }
  __syncthreads();
  {
    int nl = t >> 1, hf = t & 1;
    int colf = n0 + nl;
    int hh = colf >> 6, d = colf & 63;
    size_t rb = ((size_t)(bidx * 12 + hh) * 64 + d) * 1024 + s0;
#pragma unroll
    for (int cc = 0; cc < 8; ++cc) {
      int c = hf * 8 + cc;
      int cs = c ^ (nl & 7);
      *(short8*)&vtp[rb + c * 8] = *(const short8*)&smem[nl * 128 + cs * 8];
    }
  }
}

// ---------------------------------------------------------------------------
// MFMA flash attention (fp16), double-buffered K/VT staging.
// QK^T = mfma(K,Qh)+mfma(K,Ql) -> D[key][q]; PV = mfma(VT,P) single-term.
// Per-lane softmax (q = lm), 2 shfl/reduce. LDS = 16+16+18 = 50 KB.
// ---------------------------------------------------------------------------
__global__ __launch_bounds__(256) void attn_mfma_kernel(
    const unsigned short* __restrict__ qhp, const unsigned short* __restrict__ qlp,
    const unsigned short* __restrict__ khp, const unsigned short* __restrict__ vtp,
    unsigned short* __restrict__ oh, unsigned short* __restrict__ ol) {
  __shared__ __align__(16) short sK[8192], sVT[8192];
  __shared__ __align__(16) short sP[4][2304];
  const int t  = threadIdx.x;
  const int wv = t >> 6, l = t & 63, lm = l & 15, g = l >> 4;
  const int bh  = blockIdx.x >> 3;
  const int qw0 = (blockIdx.x & 7) * 128 + wv * 32;

  half8 qfh[2][2], qfl[2][2];
#pragma unroll
  for (int i = 0; i < 2; ++i) {
    size_t base = ((size_t)bh * 1024 + qw0 + i * 16 + lm) * 64;
#pragma unroll
    for (int tt = 0; tt < 2; ++tt) {
      qfh[i][tt] = *(const half8*)&qhp[base + tt * 32 + g * 8];
      qfl[i][tt] = *(const half8*)&qlp[base + tt * 32 + g * 8];
    }
  }

  float mrun[2] = {-1e30f, -1e30f}, lrun[2] = {0.f, 0.f};
  floatx4 o[2][4];
#pragma unroll
  for (int i = 0; i < 2; ++i)
#pragma unroll
    for (int jd = 0; jd < 4; ++jd) o[i][jd] = (floatx4){0.f, 0.f, 0.f, 0.f};

  short* sPw = sP[wv];

  // stage K (chunks 0..511) and VT (512..1023) for tile kt into buffer buf
  auto stage_kv = [&](int kt, int buf) {
#pragma unroll
    for (int qi = 0; qi < 4; ++qi) {
      int cz = qi * 256 + t;
      int plane = cz >> 9;
      int c = cz & 511;
      int row = c >> 3, s = c & 7;
      int gs = s ^ (row & 7);
      const unsigned short* gp = plane
          ? vtp + ((size_t)bh * 64 + row) * 1024 + kt * 64 + gs * 8
          : khp + ((size_t)bh * 1024 + kt * 64 + row) * 64 + gs * 8;
      short* dst = (plane ? sVT : sK) + buf * 4096 + c * 8;
      __builtin_amdgcn_global_load_lds((as1_cu32*)(const void*)gp,
                                       (as3_u32*)(void*)dst, 16, 0, 0);
    }
  };

  stage_kv(0, 0);

#pragma unroll 1
  for (int kt = 0; kt < 16; ++kt) {
    __syncthreads();                 // buf(cur) loads drained; prev reads done
    const int cur = kt & 1, nxt = cur ^ 1;
    if (kt + 1 < 16) stage_kv(kt + 1, nxt);
    const short* cK  = sK  + cur * 4096;
    const short* cVT = sVT + cur * 4096;

    // ---- QK^T (2 terms, Q exact) ----
    floatx4 sacc[2][4];
#pragma unroll
    for (int i = 0; i < 2; ++i)
#pragma unroll
      for (int j = 0; j < 4; ++j) sacc[i][j] = (floatx4){0.f, 0.f, 0.f, 0.f};
#pragma unroll
    for (int tt = 0; tt < 2; ++tt) {
#pragma unroll
      for (int j = 0; j < 4; ++j) {
        int row = j * 16 + lm;
        int so = ((4 * tt + g) ^ (row & 7)) * 8;
        half8 kf = *(const half8*)&cK[row * 64 + so];
#pragma unroll
        for (int i = 0; i < 2; ++i) {
          sacc[i][j] = __builtin_amdgcn_mfma_f32_16x16x32_f16(kf, qfh[i][tt], sacc[i][j], 0, 0, 0);
          sacc[i][j] = __builtin_amdgcn_mfma_f32_16x16x32_f16(kf, qfl[i][tt], sacc[i][j], 0, 0, 0);
        }
      }
    }

    // ---- per-lane online softmax (q-row = qw0 + i*16 + lm) ----
    float p[2][16];
#pragma unroll
    for (int i = 0; i < 2; ++i) {
      float mt = -1e30f;
#pragma unroll
      for (int j = 0; j < 4; ++j)
#pragma unroll
        for (int r = 0; r < 4; ++r) mt = fmaxf(mt, sacc[i][j][r]);
      mt = fmaxf(mt, __shfl_xor(mt, 16));
      mt = fmaxf(mt, __shfl_xor(mt, 32));
      float mn = fmaxf(mrun[i], mt);
      float corr = __expf(mrun[i] - mn);
      mrun[i] = mn;
      float ps = 0.f;
#pragma unroll
      for (int j = 0; j < 4; ++j)
#pragma unroll
        for (int r = 0; r < 4; ++r) {
          float e = __expf(sacc[i][j][r] - mn);
          p[i][j * 4 + r] = e; ps += e;
        }
      ps += __shfl_xor(ps, 16);
      ps += __shfl_xor(ps, 32);
      lrun[i] = lrun[i] * corr + ps;
#pragma unroll
      for (int jd = 0; jd < 4; ++jd)
#pragma unroll
        for (int r = 0; r < 4; ++r) o[i][jd][r] *= corr;
    }

    // ---- P -> per-wave LDS (single fp16 plane) ----
#pragma unroll
    for (int i = 0; i < 2; ++i)
#pragma unroll
      for (int j = 0; j < 4; ++j) {
        unsigned short hv[4];
#pragma unroll
        for (int r = 0; r < 4; ++r) hv[r] = h16(p[i][j * 4 + r]);
        *(uint2*)&sPw[(i * 16 + lm) * 72 + j * 16 + g * 4] =
            make_uint2((unsigned)hv[0] | ((unsigned)hv[1] << 16),
                       (unsigned)hv[2] | ((unsigned)hv[3] << 16));
      }
    half8 pf[2][2];
#pragma unroll
    for (int i = 0; i < 2; ++i)
#pragma unroll
      for (int tt = 0; tt < 2; ++tt)
        pf[i][tt] = *(const half8*)&sPw[(i * 16 + lm) * 72 + tt * 32 + g * 8];

    // ---- PV (single term) ----
#pragma unroll
    for (int tt = 0; tt < 2; ++tt) {
#pragma unroll
      for (int jd = 0; jd < 4; ++jd) {
        int row = jd * 16 + lm;
        int so = ((4 * tt + g) ^ (row & 7)) * 8;
        half8 vf = *(const half8*)&cVT[row * 64 + so];
#pragma unroll
        for (int i = 0; i < 2; ++i)
          o[i][jd] = __builtin_amdgcn_mfma_f32_16x16x32_f16(vf, pf[i][tt], o[i][jd], 0, 0, 0);
      }
    }
  }

  // ---- epilogue: normalize, hi/lo fp16 out [B,S,768] ----
  const int b = bh / 12, h = bh % 12;
#pragma unroll
  for (int i = 0; i < 2; ++i) {
    float inv = 1.f / lrun[i];
    int q = qw0 + i * 16 + lm;
#pragma unroll
    for (int jd = 0; jd < 4; ++jd) {
      unsigned short hv[4], lv[4];
#pragma unroll
      for (int r = 0; r < 4; ++r) hsplit(o[i][jd][r] * inv, hv[r], lv[r]);
      size_t off = ((size_t)(b * 1024) + q) * 768 + h * 64 + jd * 16 + g * 4;
      *(uint2*)&oh[off] = make_uint2((unsigned)hv[0] | ((unsigned)hv[1] << 16),
                                     (unsigned)hv[2] | ((unsigned)hv[3] << 16));
      *(uint2*)&ol[off] = make_uint2((unsigned)lv[0] | ((unsigned)lv[1] << 16),
                                     (unsigned)lv[2] | ((unsigned)lv[3] << 16));
    }
  }
}

// ---------------------------------------------------------------------------
// Output projection (2-term fp16): out = A @ Wo + bo, fp32 out.
// ---------------------------------------------------------------------------
__global__ __launch_bounds__(256) void proj_mfma_kernel(
    const unsigned short* __restrict__ ah_, const unsigned short* __restrict__ al_,
    const unsigned short* __restrict__ wo_, const float* __restrict__ bo,
    float* __restrict__ out) {
  __shared__ __align__(16) short sAh[8192], sAl[8192], sB[8192];
  const int t  = threadIdx.x;
  const int m0 = blockIdx.x * 128;
  const int n0 = blockIdx.y * 128;

  GEMM_MAIN_LOOP_DB(ah_, al_, wo_, m0, n0)

#pragma unroll
  for (int j = 0; j < 4; ++j) {
    int n = n0 + wn + j * 16 + lm;
    float bsv = bo[n];
#pragma unroll
    for (int i = 0; i < 4; ++i) {
#pragma unroll
      for (int r = 0; r < 4; ++r) {
        int m = m0 + wm + i * 16 + g * 4 + r;
        out[(size_t)m * 768 + n] = acc[i][j][r] + bsv;
      }
    }
  }
}

// ---------------------------------------------------------------------------
extern "C" void kernel_launch(void* const* d_in, const int* in_sizes, int n_in,
                              void* d_out, int out_size, void* d_ws, size_t ws_size,
                              hipStream_t stream) {
  const float* x  = (const float*)d_in[0];
  const float* Wq = (const float*)d_in[1];
  const float* bq = (const float*)d_in[2];
  const float* Wk = (const float*)d_in[3];
  const float* bk = (const float*)d_in[4];
  const float* Wv = (const float*)d_in[5];
  const float* bv = (const float*)d_in[6];
  const float* Wo = (const float*)d_in[7];
  const float* bo = (const float*)d_in[8];
  float* out = (float*)d_out;

  char* w = (char*)d_ws;
  float* tab          = (float*)(w);                      // 262144
  unsigned short* wt  = (unsigned short*)(w + 262144);    // 3538944 (Wq|Wk|Wv ^T fp16)
  unsigned short* wo  = (unsigned short*)(w + 3801088);   // 1179648
  unsigned short* xh  = (unsigned short*)(w + 4980736);   // 12582912 (reused: attn out hi)
  unsigned short* xl  = (unsigned short*)(w + 17563648);  // 12582912 (reused: attn out lo)
  unsigned short* qh  = (unsigned short*)(w + 30146560);  // 12582912
  unsigned short* ql  = (unsigned short*)(w + 42729472);  // 12582912
  unsigned short* kh  = (unsigned short*)(w + 55312384);  // 12582912
  unsigned short* vt  = (unsigned short*)(w + 67895296);  // 12582912 -> end 80478208

  rope_tab_kernel<<<dim3(128), dim3(256), 0, stream>>>(tab);
  xconv_kernel<<<dim3(6144), dim3(256), 0, stream>>>(x, xh, xl);
  wconv_kernel<<<dim3(24, 24, 4), dim3(256), 0, stream>>>(
      Wq, Wk, Wv, Wo, wt, wo);
  qk_mfma_kernel<<<dim3(64, 12), dim3(256), 0, stream>>>(
      xh, xl, wt, bq, bk, tab, qh, ql, kh);
  v_mfma_kernel<<<dim3(64, 6), dim3(256), 0, stream>>>(
      xh, xl, wt + (size_t)2 * 589824, bv, vt);
  attn_mfma_kernel<<<dim3(768), dim3(256), 0, stream>>>(
      qh, ql, kh, vt, xh, xl);
  proj_mfma_kernel<<<dim3(64, 6), dim3(256), 0, stream>>>(
      xh, xl, wo, bo, out);
}